// Round 1
// baseline (529.308 us; speedup 1.0000x reference)
//
#include <hip/hip_runtime.h>
#include <hip/hip_bf16.h>
#include <stdint.h>

// BilinearDiscriminator: out = sigmoid((x*mask_x) @ W^T @ (y*mask_y)^T)
// fp32 precision via bf16 hi/lo split (hh + lh + hl segments).
// R4: GEMM2 rewritten as 256x256-tile / 512-thread / double-buffered LDS with
// COUNTED vmcnt (never drained to 0 in the main loop) -- T3/T4/T5 from the
// 8-phase template. Previous structure drained vmcnt(0) at every K-step
// (__syncthreads), exposing full global-load latency 16x per block
// (MfmaUtil 35.5%). Now: prefetch depth 2, vmcnt(8) waits, raw s_barrier,
// setprio around MFMA clusters. GEMM1 + prep unchanged.

typedef __bf16 bf16_t;
typedef bf16_t bf16x8 __attribute__((ext_vector_type(8)));
typedef bf16_t bf16x4 __attribute__((ext_vector_type(4)));
typedef float f32x4 __attribute__((ext_vector_type(4)));

#define N_ROWS 8192
#define M_ROWS 8192
#define DDIM 512
#define BK 32

__device__ __forceinline__ void async_cp16(const bf16_t* g, bf16_t* l) {
    __builtin_amdgcn_global_load_lds(
        (const __attribute__((address_space(1))) unsigned int*)(uintptr_t)g,
        (__attribute__((address_space(3))) unsigned int*)(uint32_t)(uintptr_t)l,
        16, 0, 0);
}

// One kernel for all three dropout+split preps (saves launch gaps).
// blocks [0,4096): x  [4096,8192): y  [8192,8448): W
__global__ __launch_bounds__(256) void prep_all(
    const float* __restrict__ x, const float* __restrict__ mx,
    const float* __restrict__ y, const float* __restrict__ my,
    const float* __restrict__ W,
    bf16_t* __restrict__ xd_hi, bf16_t* __restrict__ xd_lo,
    bf16_t* __restrict__ yd_hi, bf16_t* __restrict__ yd_lo,
    bf16_t* __restrict__ W_hi, bf16_t* __restrict__ W_lo) {
    const int b = blockIdx.x;
    const float* v; const float* m; bf16_t* hi; bf16_t* lo; int idx;
    if (b < 4096)      { v = x; m = mx;      hi = xd_hi; lo = xd_lo; idx = b * 256 + threadIdx.x; }
    else if (b < 8192) { v = y; m = my;      hi = yd_hi; lo = yd_lo; idx = (b - 4096) * 256 + threadIdx.x; }
    else               { v = W; m = nullptr; hi = W_hi;  lo = W_lo;  idx = (b - 8192) * 256 + threadIdx.x; }
    float4 xv = ((const float4*)v)[idx];
    if (m) {
        float4 mv = ((const float4*)m)[idx];
        xv.x *= mv.x; xv.y *= mv.y; xv.z *= mv.z; xv.w *= mv.w;
    }
    float vals[4] = {xv.x, xv.y, xv.z, xv.w};
    bf16x4 h, l;
#pragma unroll
    for (int i = 0; i < 4; ++i) {
        bf16_t hh = (bf16_t)vals[i];
        h[i] = hh;
        l[i] = (bf16_t)(vals[i] - (float)hh);
    }
    *(bf16x4*)(hi + (size_t)idx * 4) = h;
    *(bf16x4*)(lo + (size_t)idx * 4) = l;
}

// ---------------------------------------------------------------------------
// GEMM1 kernel (old structure, 64x64 tiles): xt = xd @ W^T with hi/lo split
// epilogue. Small (1/16 the FLOPs of GEMM2); left as-is.
// ---------------------------------------------------------------------------
template <int EPI, int MI, int NI, int TM, int TN>
__global__ __launch_bounds__(256) void gemm_fused(
    const bf16_t* __restrict__ Ahi, const bf16_t* __restrict__ Alo,
    const bf16_t* __restrict__ Bhi, const bf16_t* __restrict__ Blo,
    float* __restrict__ Cf,
    bf16_t* __restrict__ Chi, bf16_t* __restrict__ Clo,
    int ldc) {
    constexpr int BM = MI * 32;
    constexpr int BN = NI * 32;
    constexpr int AS = BM * 4 / 256;
    constexpr int BS = BN * 4 / 256;
    constexpr int SN = TN / 8;

    __shared__ __align__(16) bf16_t Ash[BM * BK];
    __shared__ __align__(16) bf16_t Asl[BM * BK];
    __shared__ __align__(16) bf16_t Bsh[BN * BK];
    __shared__ __align__(16) bf16_t Bsl[BN * BK];

    const int tid = threadIdx.x;
    const int lane = tid & 63;
    const int wave = tid >> 6;
    const int wm = (wave & 1) * MI * 16;
    const int wn = (wave >> 1) * NI * 16;

    const int bid = blockIdx.x;
    const int jj = bid & 7;
    const int ii = (bid >> 3) & 7;
    const int sc = (bid >> 6) % SN;
    const int sr = (bid >> 6) / SN;
    const int bm = sr * 8 + ii;
    const int bn = sc * 8 + jj;

    const int m0 = lane & 15;
    const int kc = lane >> 4;
    const int fsw = kc ^ ((m0 >> 1) & 3);

    f32x4 acc[MI][NI];
#pragma unroll
    for (int i = 0; i < MI; ++i)
#pragma unroll
        for (int j = 0; j < NI; ++j)
            acc[i][j] = (f32x4){0.f, 0.f, 0.f, 0.f};

    for (int k0 = 0; k0 < DDIM; k0 += BK) {
        __syncthreads();
#pragma unroll
        for (int s = 0; s < AS; ++s) {
            const int slot = tid + s * 256;
            const int r = slot >> 2;
            const int c = (slot & 3) ^ ((r >> 1) & 3);
            const size_t g = (size_t)(bm * BM + r) * DDIM + k0 + c * 8;
            async_cp16(Ahi + g, &Ash[slot * 8]);
            async_cp16(Alo + g, &Asl[slot * 8]);
        }
#pragma unroll
        for (int s = 0; s < BS; ++s) {
            const int slot = tid + s * 256;
            const int r = slot >> 2;
            const int c = (slot & 3) ^ ((r >> 1) & 3);
            const size_t g = (size_t)(bn * BN + r) * DDIM + k0 + c * 8;
            async_cp16(Bhi + g, &Bsh[slot * 8]);
            async_cp16(Blo + g, &Bsl[slot * 8]);
        }
        __syncthreads();

        bf16x8 ah[MI], bh[NI];
#pragma unroll
        for (int mi = 0; mi < MI; ++mi)
            ah[mi] = *(const bf16x8*)&Ash[((wm + mi * 16 + m0) * 4 + fsw) * 8];
#pragma unroll
        for (int ni = 0; ni < NI; ++ni)
            bh[ni] = *(const bf16x8*)&Bsh[((wn + ni * 16 + m0) * 4 + fsw) * 8];

#pragma unroll
        for (int mi = 0; mi < MI; ++mi)
#pragma unroll
            for (int ni = 0; ni < NI; ++ni)
                acc[mi][ni] = __builtin_amdgcn_mfma_f32_16x16x32_bf16(
                    ah[mi], bh[ni], acc[mi][ni], 0, 0, 0);
        {
            bf16x8 al[MI];
#pragma unroll
            for (int mi = 0; mi < MI; ++mi)
                al[mi] = *(const bf16x8*)&Asl[((wm + mi * 16 + m0) * 4 + fsw) * 8];
#pragma unroll
            for (int mi = 0; mi < MI; ++mi)
#pragma unroll
                for (int ni = 0; ni < NI; ++ni)
                    acc[mi][ni] = __builtin_amdgcn_mfma_f32_16x16x32_bf16(
                        al[mi], bh[ni], acc[mi][ni], 0, 0, 0);
        }
        {
            bf16x8 bl[NI];
#pragma unroll
            for (int ni = 0; ni < NI; ++ni)
                bl[ni] = *(const bf16x8*)&Bsl[((wn + ni * 16 + m0) * 4 + fsw) * 8];
#pragma unroll
            for (int mi = 0; mi < MI; ++mi)
#pragma unroll
                for (int ni = 0; ni < NI; ++ni)
                    acc[mi][ni] = __builtin_amdgcn_mfma_f32_16x16x32_bf16(
                        ah[mi], bl[ni], acc[mi][ni], 0, 0, 0);
        }
    }

    const int ccol = lane & 15;
    const int crow = (lane >> 4) * 4;
#pragma unroll
    for (int mi = 0; mi < MI; ++mi) {
#pragma unroll
        for (int ni = 0; ni < NI; ++ni) {
#pragma unroll
            for (int r = 0; r < 4; ++r) {
                const int i = bm * BM + wm + mi * 16 + crow + r;
                const int j = bn * BN + wn + ni * 16 + ccol;
                const float v = acc[mi][ni][r];
                if (EPI == 1) {
                    const float sv = 1.0f / (1.0f + __expf(-v));
                    __builtin_nontemporal_store(sv, &Cf[(size_t)i * ldc + j]);
                } else {
                    bf16_t h = (bf16_t)v;
                    bf16_t lo = (bf16_t)(v - (float)h);
                    Chi[(size_t)i * ldc + j] = h;
                    Clo[(size_t)i * ldc + j] = lo;
                }
            }
        }
    }
}

// ---------------------------------------------------------------------------
// GEMM2: out = sigmoid(xt @ yd^T), 8192x8192, K=512.
// 256x256 tile, 512 threads = 8 waves (2 wave-rows x 4 wave-cols), each wave
// owns a 128x64 sub-tile (8x4 16x16 fragments). BK=32, double-buffered LDS
// (128 KiB): Ah/Al/Bh/Bl x 2. XOR-swizzled 16B chunks (slot c = c^((r>>1)&3))
// -> 0 bank conflicts (verified scheme from R3).
// Schedule per K-step: s_waitcnt vmcnt(8) (leave next tile's 8 loads in
// flight!) -> s_barrier -> ds_read frags + 96 MFMA (hh, hl, lh; setprio(1)
// clusters; al reads overlap hl cluster) -> s_barrier -> issue stage(t+2)
// (8 global_load_lds, NOT waited -- they land under the next K-step's MFMA).
// vmcnt reaches 0 only once, at the final K-step.
// ---------------------------------------------------------------------------
__global__ __launch_bounds__(512, 2) void gemm2_sig(
    const bf16_t* __restrict__ Ahi, const bf16_t* __restrict__ Alo,
    const bf16_t* __restrict__ Bhi, const bf16_t* __restrict__ Blo,
    float* __restrict__ Cf) {
    constexpr int BM = 256;           // = BN
    constexpr int LDT = BM * BK;      // 8192 bf16 = 16 KiB per array per buf

    __shared__ __align__(16) bf16_t Ash[2][LDT];
    __shared__ __align__(16) bf16_t Asl[2][LDT];
    __shared__ __align__(16) bf16_t Bsh[2][LDT];
    __shared__ __align__(16) bf16_t Bsl[2][LDT];

    const int tid = threadIdx.x;
    const int lane = tid & 63;
    const int wave = tid >> 6;
    const int wm = (wave >> 2) * 128;   // wave-row: 0 / 128
    const int wn = (wave & 3) * 64;     // wave-col: 0 / 64 / 128 / 192

    // supertile order (32x32 tile grid, 1024 blocks): bn fastest -> XCD id
    const int bid = blockIdx.x;
    const int jj = bid & 7;
    const int ii = (bid >> 3) & 7;
    const int sc = (bid >> 6) & 3;      // SN = 32/8 = 4
    const int sr = (bid >> 6) >> 2;
    const int bm = sr * 8 + ii;
    const int bn = sc * 8 + jj;

    const int m0 = lane & 15;
    const int kc = lane >> 4;
    const int fsw = kc ^ ((m0 >> 1) & 3);  // swizzled chunk for fragment reads

    // per-thread staging map: 2 16B slots per array per K-step (1024 slots)
    int aOff[2], bOff[2], lofs[2];
#pragma unroll
    for (int s = 0; s < 2; ++s) {
        const int slot = tid + s * 512;
        const int r = slot >> 2;
        const int c = (slot & 3) ^ ((r >> 1) & 3);  // pre-swizzled global src
        aOff[s] = (bm * BM + r) * DDIM + c * 8;
        bOff[s] = (bn * BM + r) * DDIM + c * 8;
        lofs[s] = slot * 8;
    }

    f32x4 acc[8][4];
#pragma unroll
    for (int i = 0; i < 8; ++i)
#pragma unroll
        for (int j = 0; j < 4; ++j) acc[i][j] = (f32x4){0.f, 0.f, 0.f, 0.f};

    // 8 global_load_lds instructions per wave per call (vmcnt += 8)
    auto stage = [&](bf16_t* da_h, bf16_t* da_l, bf16_t* db_h, bf16_t* db_l,
                     int k0) {
#pragma unroll
        for (int s = 0; s < 2; ++s) {
            async_cp16(Ahi + aOff[s] + k0, da_h + lofs[s]);
            async_cp16(Alo + aOff[s] + k0, da_l + lofs[s]);
            async_cp16(Bhi + bOff[s] + k0, db_h + lofs[s]);
            async_cp16(Blo + bOff[s] + k0, db_l + lofs[s]);
        }
    };

    auto compute = [&](const bf16_t* ash, const bf16_t* asl,
                       const bf16_t* bsh, const bf16_t* bsl) {
        bf16x8 ah[8], bh[4], bl[4];
#pragma unroll
        for (int mi = 0; mi < 8; ++mi)
            ah[mi] = *(const bf16x8*)&ash[((wm + mi * 16 + m0) * 4 + fsw) * 8];
#pragma unroll
        for (int ni = 0; ni < 4; ++ni)
            bh[ni] = *(const bf16x8*)&bsh[((wn + ni * 16 + m0) * 4 + fsw) * 8];
#pragma unroll
        for (int ni = 0; ni < 4; ++ni)
            bl[ni] = *(const bf16x8*)&bsl[((wn + ni * 16 + m0) * 4 + fsw) * 8];
        // hh
        __builtin_amdgcn_s_setprio(1);
#pragma unroll
        for (int mi = 0; mi < 8; ++mi)
#pragma unroll
            for (int ni = 0; ni < 4; ++ni)
                acc[mi][ni] = __builtin_amdgcn_mfma_f32_16x16x32_bf16(
                    ah[mi], bh[ni], acc[mi][ni], 0, 0, 0);
        __builtin_amdgcn_s_setprio(0);
        // al reads issued here -> overlap the hl MFMA cluster
        bf16x8 al[8];
#pragma unroll
        for (int mi = 0; mi < 8; ++mi)
            al[mi] = *(const bf16x8*)&asl[((wm + mi * 16 + m0) * 4 + fsw) * 8];
        __builtin_amdgcn_s_setprio(1);
        // hl (ah x bl)
#pragma unroll
        for (int mi = 0; mi < 8; ++mi)
#pragma unroll
            for (int ni = 0; ni < 4; ++ni)
                acc[mi][ni] = __builtin_amdgcn_mfma_f32_16x16x32_bf16(
                    ah[mi], bl[ni], acc[mi][ni], 0, 0, 0);
        // lh (al x bh)
#pragma unroll
        for (int mi = 0; mi < 8; ++mi)
#pragma unroll
            for (int ni = 0; ni < 4; ++ni)
                acc[mi][ni] = __builtin_amdgcn_mfma_f32_16x16x32_bf16(
                    al[mi], bh[ni], acc[mi][ni], 0, 0, 0);
        __builtin_amdgcn_s_setprio(0);
    };

    // prologue: prefetch depth 2 (16 loads in flight)
    stage(Ash[0], Asl[0], Bsh[0], Bsl[0], 0);
    stage(Ash[1], Asl[1], Bsh[1], Bsl[1], BK);

#pragma unroll 1
    for (int t2 = 0; t2 < 7; ++t2) {  // K-steps 0..13, two per iteration
        const int kb = t2 * 2 * BK;
        asm volatile("s_waitcnt vmcnt(8)" ::: "memory");  // buf0 ready, buf1 in flight
        __builtin_amdgcn_s_barrier();
        __builtin_amdgcn_sched_barrier(0);
        compute(Ash[0], Asl[0], Bsh[0], Bsl[0]);
        __builtin_amdgcn_s_barrier();                     // all waves done reading buf0
        stage(Ash[0], Asl[0], Bsh[0], Bsl[0], kb + 2 * BK);
        asm volatile("s_waitcnt vmcnt(8)" ::: "memory");
        __builtin_amdgcn_s_barrier();
        __builtin_amdgcn_sched_barrier(0);
        compute(Ash[1], Asl[1], Bsh[1], Bsl[1]);
        __builtin_amdgcn_s_barrier();
        stage(Ash[1], Asl[1], Bsh[1], Bsl[1], kb + 3 * BK);
    }
    // K-step 14 (buf0): stage(15) still in flight
    asm volatile("s_waitcnt vmcnt(8)" ::: "memory");
    __builtin_amdgcn_s_barrier();
    __builtin_amdgcn_sched_barrier(0);
    compute(Ash[0], Asl[0], Bsh[0], Bsl[0]);
    // K-step 15 (buf1): the only full drain
    asm volatile("s_waitcnt vmcnt(0)" ::: "memory");
    __builtin_amdgcn_s_barrier();
    __builtin_amdgcn_sched_barrier(0);
    compute(Ash[1], Asl[1], Bsh[1], Bsl[1]);

    // epilogue: sigmoid -> fp32, nontemporal (never re-read)
    const int ccol = lane & 15;
    const int crow = (lane >> 4) * 4;
#pragma unroll
    for (int mi = 0; mi < 8; ++mi) {
#pragma unroll
        for (int ni = 0; ni < 4; ++ni) {
#pragma unroll
            for (int r = 0; r < 4; ++r) {
                const size_t i = (size_t)(bm * BM + wm + mi * 16 + crow + r);
                const size_t j = (size_t)(bn * BM + wn + ni * 16 + ccol);
                const float v = acc[mi][ni][r];
                const float sv = 1.0f / (1.0f + __expf(-v));
                __builtin_nontemporal_store(sv, &Cf[i * M_ROWS + j]);
            }
        }
    }
}

extern "C" void kernel_launch(void* const* d_in, const int* in_sizes, int n_in,
                              void* d_out, int out_size, void* d_ws, size_t ws_size,
                              hipStream_t stream) {
    const float* x  = (const float*)d_in[0];
    const float* y  = (const float*)d_in[1];
    const float* mx = (const float*)d_in[2];
    const float* my = (const float*)d_in[3];
    const float* W  = (const float*)d_in[4];
    float* out = (float*)d_out;

    const size_t ND = (size_t)N_ROWS * DDIM;  // 4,194,304
    const size_t WD = (size_t)DDIM * DDIM;    // 262,144

    bf16_t* ws = (bf16_t*)d_ws;
    bf16_t* xd_hi = ws;
    bf16_t* xd_lo = ws + ND;
    bf16_t* yd_hi = ws + 2 * ND;
    bf16_t* yd_lo = ws + 3 * ND;
    bf16_t* xt_hi = ws + 4 * ND;
    bf16_t* xt_lo = ws + 5 * ND;
    bf16_t* W_hi  = ws + 6 * ND;
    bf16_t* W_lo  = ws + 6 * ND + WD;

    // fused prep: dropout + hi/lo split for x, y, W in one launch
    prep_all<<<4096 + 4096 + 256, 256, 0, stream>>>(
        x, mx, y, my, W, xd_hi, xd_lo, yd_hi, yd_lo, W_hi, W_lo);

    // GEMM1: xt[n,k] = sum_d xd[n,d]*W[k,d]  (8192x512), 64x64 tiles
    gemm_fused<0, 2, 2, 128, 8><<<128 * 8, 256, 0, stream>>>(
        xd_hi, xd_lo, W_hi, W_lo, nullptr, xt_hi, xt_lo, DDIM);

    // GEMM2: out = sigmoid(xt @ yd^T)  (8192x8192), 256x256 tiles, 1024 blocks
    gemm2_sig<<<1024, 512, 0, stream>>>(xt_hi, xt_lo, yd_hi, yd_lo, out);
}

// Round 2
// 510.552 us; speedup vs baseline: 1.0367x; 1.0367x over previous
//
#include <hip/hip_runtime.h>
#include <hip/hip_bf16.h>
#include <stdint.h>

// BilinearDiscriminator: out = sigmoid((x*mask_x) @ W^T @ (y*mask_y)^T)
// fp32 precision via bf16 hi/lo split (hh + lh + hl segments).
// R5: GEMM2 ported to the verified m201-style PHASE-INTERLEAVED schedule.
// R4's counted-vmcnt on a 2-barrier body changed nothing (MfmaUtil 34%,
// dur 259us == documented m97-structure ceiling). Now: 6 phases per BK=32
// K-tile, each {ds_read subtile -> stage 1 array -> s_barrier -> lgkmcnt(0)
// -> setprio(1) 16 MFMA setprio(0) -> s_barrier}; vmcnt(4) twice per tile
// (before the barrier preceding dependent reads), vmcnt(0) only in the
// peeled last tile. ds_read/stage of phase p+1 overlap MFMA of phase p
// across waves. GEMM1 + prep unchanged.

typedef __bf16 bf16_t;
typedef bf16_t bf16x8 __attribute__((ext_vector_type(8)));
typedef bf16_t bf16x4 __attribute__((ext_vector_type(4)));
typedef float f32x4 __attribute__((ext_vector_type(4)));

#define N_ROWS 8192
#define M_ROWS 8192
#define DDIM 512
#define BK 32

__device__ __forceinline__ void async_cp16(const bf16_t* g, bf16_t* l) {
    __builtin_amdgcn_global_load_lds(
        (const __attribute__((address_space(1))) unsigned int*)(uintptr_t)g,
        (__attribute__((address_space(3))) unsigned int*)(uint32_t)(uintptr_t)l,
        16, 0, 0);
}

#define VMCNT_(n) asm volatile("s_waitcnt vmcnt(" #n ")" ::: "memory")
#define VMCNT(n) VMCNT_(n)
#define LGKM0()  asm volatile("s_waitcnt lgkmcnt(0)" ::: "memory")
#define SB0()    __builtin_amdgcn_sched_barrier(0)
#define BAR()    __builtin_amdgcn_s_barrier()

// One kernel for all three dropout+split preps (saves launch gaps).
// blocks [0,4096): x  [4096,8192): y  [8192,8448): W
__global__ __launch_bounds__(256) void prep_all(
    const float* __restrict__ x, const float* __restrict__ mx,
    const float* __restrict__ y, const float* __restrict__ my,
    const float* __restrict__ W,
    bf16_t* __restrict__ xd_hi, bf16_t* __restrict__ xd_lo,
    bf16_t* __restrict__ yd_hi, bf16_t* __restrict__ yd_lo,
    bf16_t* __restrict__ W_hi, bf16_t* __restrict__ W_lo) {
    const int b = blockIdx.x;
    const float* v; const float* m; bf16_t* hi; bf16_t* lo; int idx;
    if (b < 4096)      { v = x; m = mx;      hi = xd_hi; lo = xd_lo; idx = b * 256 + threadIdx.x; }
    else if (b < 8192) { v = y; m = my;      hi = yd_hi; lo = yd_lo; idx = (b - 4096) * 256 + threadIdx.x; }
    else               { v = W; m = nullptr; hi = W_hi;  lo = W_lo;  idx = (b - 8192) * 256 + threadIdx.x; }
    float4 xv = ((const float4*)v)[idx];
    if (m) {
        float4 mv = ((const float4*)m)[idx];
        xv.x *= mv.x; xv.y *= mv.y; xv.z *= mv.z; xv.w *= mv.w;
    }
    float vals[4] = {xv.x, xv.y, xv.z, xv.w};
    bf16x4 h, l;
#pragma unroll
    for (int i = 0; i < 4; ++i) {
        bf16_t hh = (bf16_t)vals[i];
        h[i] = hh;
        l[i] = (bf16_t)(vals[i] - (float)hh);
    }
    *(bf16x4*)(hi + (size_t)idx * 4) = h;
    *(bf16x4*)(lo + (size_t)idx * 4) = l;
}

// ---------------------------------------------------------------------------
// GEMM1 kernel (old structure, 64x64 tiles): xt = xd @ W^T with hi/lo split
// epilogue. Small (1/16 the FLOPs of GEMM2); left as-is.
// ---------------------------------------------------------------------------
template <int EPI, int MI, int NI, int TM, int TN>
__global__ __launch_bounds__(256) void gemm_fused(
    const bf16_t* __restrict__ Ahi, const bf16_t* __restrict__ Alo,
    const bf16_t* __restrict__ Bhi, const bf16_t* __restrict__ Blo,
    float* __restrict__ Cf,
    bf16_t* __restrict__ Chi, bf16_t* __restrict__ Clo,
    int ldc) {
    constexpr int BM = MI * 32;
    constexpr int BN = NI * 32;
    constexpr int AS = BM * 4 / 256;
    constexpr int BS = BN * 4 / 256;
    constexpr int SN = TN / 8;

    __shared__ __align__(16) bf16_t Ash[BM * BK];
    __shared__ __align__(16) bf16_t Asl[BM * BK];
    __shared__ __align__(16) bf16_t Bsh[BN * BK];
    __shared__ __align__(16) bf16_t Bsl[BN * BK];

    const int tid = threadIdx.x;
    const int lane = tid & 63;
    const int wave = tid >> 6;
    const int wm = (wave & 1) * MI * 16;
    const int wn = (wave >> 1) * NI * 16;

    const int bid = blockIdx.x;
    const int jj = bid & 7;
    const int ii = (bid >> 3) & 7;
    const int sc = (bid >> 6) % SN;
    const int sr = (bid >> 6) / SN;
    const int bm = sr * 8 + ii;
    const int bn = sc * 8 + jj;

    const int m0 = lane & 15;
    const int kc = lane >> 4;
    const int fsw = kc ^ ((m0 >> 1) & 3);

    f32x4 acc[MI][NI];
#pragma unroll
    for (int i = 0; i < MI; ++i)
#pragma unroll
        for (int j = 0; j < NI; ++j)
            acc[i][j] = (f32x4){0.f, 0.f, 0.f, 0.f};

    for (int k0 = 0; k0 < DDIM; k0 += BK) {
        __syncthreads();
#pragma unroll
        for (int s = 0; s < AS; ++s) {
            const int slot = tid + s * 256;
            const int r = slot >> 2;
            const int c = (slot & 3) ^ ((r >> 1) & 3);
            const size_t g = (size_t)(bm * BM + r) * DDIM + k0 + c * 8;
            async_cp16(Ahi + g, &Ash[slot * 8]);
            async_cp16(Alo + g, &Asl[slot * 8]);
        }
#pragma unroll
        for (int s = 0; s < BS; ++s) {
            const int slot = tid + s * 256;
            const int r = slot >> 2;
            const int c = (slot & 3) ^ ((r >> 1) & 3);
            const size_t g = (size_t)(bn * BN + r) * DDIM + k0 + c * 8;
            async_cp16(Bhi + g, &Bsh[slot * 8]);
            async_cp16(Blo + g, &Bsl[slot * 8]);
        }
        __syncthreads();

        bf16x8 ah[MI], bh[NI];
#pragma unroll
        for (int mi = 0; mi < MI; ++mi)
            ah[mi] = *(const bf16x8*)&Ash[((wm + mi * 16 + m0) * 4 + fsw) * 8];
#pragma unroll
        for (int ni = 0; ni < NI; ++ni)
            bh[ni] = *(const bf16x8*)&Bsh[((wn + ni * 16 + m0) * 4 + fsw) * 8];

#pragma unroll
        for (int mi = 0; mi < MI; ++mi)
#pragma unroll
            for (int ni = 0; ni < NI; ++ni)
                acc[mi][ni] = __builtin_amdgcn_mfma_f32_16x16x32_bf16(
                    ah[mi], bh[ni], acc[mi][ni], 0, 0, 0);
        {
            bf16x8 al[MI];
#pragma unroll
            for (int mi = 0; mi < MI; ++mi)
                al[mi] = *(const bf16x8*)&Asl[((wm + mi * 16 + m0) * 4 + fsw) * 8];
#pragma unroll
            for (int mi = 0; mi < MI; ++mi)
#pragma unroll
                for (int ni = 0; ni < NI; ++ni)
                    acc[mi][ni] = __builtin_amdgcn_mfma_f32_16x16x32_bf16(
                        al[mi], bh[ni], acc[mi][ni], 0, 0, 0);
        }
        {
            bf16x8 bl[NI];
#pragma unroll
            for (int ni = 0; ni < NI; ++ni)
                bl[ni] = *(const bf16x8*)&Bsl[((wn + ni * 16 + m0) * 4 + fsw) * 8];
#pragma unroll
            for (int mi = 0; mi < MI; ++mi)
#pragma unroll
                for (int ni = 0; ni < NI; ++ni)
                    acc[mi][ni] = __builtin_amdgcn_mfma_f32_16x16x32_bf16(
                        ah[mi], bl[ni], acc[mi][ni], 0, 0, 0);
        }
    }

    const int ccol = lane & 15;
    const int crow = (lane >> 4) * 4;
#pragma unroll
    for (int mi = 0; mi < MI; ++mi) {
#pragma unroll
        for (int ni = 0; ni < NI; ++ni) {
#pragma unroll
            for (int r = 0; r < 4; ++r) {
                const int i = bm * BM + wm + mi * 16 + crow + r;
                const int j = bn * BN + wn + ni * 16 + ccol;
                const float v = acc[mi][ni][r];
                if (EPI == 1) {
                    const float sv = 1.0f / (1.0f + __expf(-v));
                    __builtin_nontemporal_store(sv, &Cf[(size_t)i * ldc + j]);
                } else {
                    bf16_t h = (bf16_t)v;
                    bf16_t lo = (bf16_t)(v - (float)h);
                    Chi[(size_t)i * ldc + j] = h;
                    Clo[(size_t)i * ldc + j] = lo;
                }
            }
        }
    }
}

// ---------------------------------------------------------------------------
// GEMM2: out = sigmoid(xt @ yd^T), 8192x8192, K=512. 256x256 tile, 8 waves
// (2Mx4N), per-wave 128x64 output. BK=32, double-buffered LDS 128 KiB.
// 6 phases per K-tile, 16 MFMA each:
//   P1: rd ah[0..3],bh[0..3] | stage Ah(t+1) | hh-lo   (ah03 x bh)
//   P2: rd ah[4..7]          | stage Bh(t+1) | hh-hi   (ah47 x bh)  [vmcnt 4]
//   P3: rd bl[0..3]          | stage Al(t+1) | hl-lo   (ah03 x bl)
//   P4:                      | stage Bl(t+1) | hl-hi   (ah47 x bl)
//   P5: rd al[0..3]          |               | lh-lo   (al03 x bh)
//   P6: rd al[4..7]          |               | lh-hi   (al47 x bh)  [vmcnt 4]
// Each phase: reads+stage BEFORE s_barrier (overlap other waves' MFMA),
// lgkmcnt(0)+sched_barrier after it, setprio(1) around the MFMA cluster.
// vmcnt waits sit immediately before a barrier -> cross-wave LDS-visibility
// is safe (every wave vouches for its own loads, then all sync).
// Issue->wait distance: 4-6 phases. vmcnt(0) only in the peeled last tile.
// ---------------------------------------------------------------------------
__global__ __launch_bounds__(512, 2) void gemm2_sig(
    const bf16_t* __restrict__ Ahi, const bf16_t* __restrict__ Alo,
    const bf16_t* __restrict__ Bhi, const bf16_t* __restrict__ Blo,
    float* __restrict__ Cf) {
    constexpr int BM = 256;           // = BN
    constexpr int LDT = BM * BK;      // 8192 bf16 = 16 KiB per array per buf

    __shared__ __align__(16) bf16_t Ash[2][LDT];
    __shared__ __align__(16) bf16_t Asl[2][LDT];
    __shared__ __align__(16) bf16_t Bsh[2][LDT];
    __shared__ __align__(16) bf16_t Bsl[2][LDT];

    const int tid = threadIdx.x;
    const int lane = tid & 63;
    const int wave = tid >> 6;
    const int wm = (wave >> 2) * 128;   // wave-row: 0 / 128
    const int wn = (wave & 3) * 64;     // wave-col: 0 / 64 / 128 / 192

    // supertile order (32x32 tile grid, 1024 blocks): bn fastest -> XCD id
    const int bid = blockIdx.x;
    const int jj = bid & 7;
    const int ii = (bid >> 3) & 7;
    const int sc = (bid >> 6) & 3;
    const int sr = (bid >> 6) >> 2;
    const int bm = sr * 8 + ii;
    const int bn = sc * 8 + jj;

    const int m0 = lane & 15;
    const int kc = lane >> 4;
    const int fsw = kc ^ ((m0 >> 1) & 3);  // swizzled chunk for fragment reads

    // per-thread staging map: 2 16B slots per array per K-tile (1024 slots)
    int aOff[2], bOff[2], lofs[2];
#pragma unroll
    for (int s = 0; s < 2; ++s) {
        const int slot = tid + s * 512;
        const int r = slot >> 2;
        const int c = (slot & 3) ^ ((r >> 1) & 3);  // pre-swizzled global src
        aOff[s] = (bm * BM + r) * DDIM + c * 8;
        bOff[s] = (bn * BM + r) * DDIM + c * 8;
        lofs[s] = slot * 8;
    }

    f32x4 acc[8][4];
#pragma unroll
    for (int i = 0; i < 8; ++i)
#pragma unroll
        for (int j = 0; j < 4; ++j) acc[i][j] = (f32x4){0.f, 0.f, 0.f, 0.f};

    auto stageA = [&](const bf16_t* g, bf16_t* l, int k0) {
#pragma unroll
        for (int s = 0; s < 2; ++s) async_cp16(g + aOff[s] + k0, l + lofs[s]);
    };
    auto stageB = [&](const bf16_t* g, bf16_t* l, int k0) {
#pragma unroll
        for (int s = 0; s < 2; ++s) async_cp16(g + bOff[s] + k0, l + lofs[s]);
    };
    auto rdA = [&](const bf16_t* s, int mi) {
        return *(const bf16x8*)&s[((wm + mi * 16 + m0) * 4 + fsw) * 8];
    };
    auto rdB = [&](const bf16_t* s, int ni) {
        return *(const bf16x8*)&s[((wn + ni * 16 + m0) * 4 + fsw) * 8];
    };

    bf16x8 ah[8], al[8], bh[4], bl[4];

#define MFMA16(AA, BB, MI0)                                               \
    _Pragma("unroll") for (int mi = 0; mi < 4; ++mi)                      \
    _Pragma("unroll") for (int ni = 0; ni < 4; ++ni)                      \
        acc[(MI0) + mi][ni] = __builtin_amdgcn_mfma_f32_16x16x32_bf16(    \
            AA[(MI0) + mi], BB[ni], acc[(MI0) + mi][ni], 0, 0, 0);

#define TILE(CUR, NXT, KNXT, STG, VM2, DOVM6)                             \
    {                                                                      \
        const bf16_t* ash = Ash[CUR]; const bf16_t* asl = Asl[CUR];       \
        const bf16_t* bsh = Bsh[CUR]; const bf16_t* bsl = Bsl[CUR];       \
        /* -- P1 -- */                                                     \
        _Pragma("unroll") for (int i = 0; i < 4; ++i) ah[i] = rdA(ash, i);\
        _Pragma("unroll") for (int i = 0; i < 4; ++i) bh[i] = rdB(bsh, i);\
        if (STG) stageA(Ahi, Ash[NXT], (KNXT));                            \
        SB0(); BAR(); LGKM0(); SB0();                                      \
        __builtin_amdgcn_s_setprio(1);                                     \
        MFMA16(ah, bh, 0);                                                 \
        __builtin_amdgcn_s_setprio(0);                                     \
        BAR();                                                             \
        /* -- P2 -- */                                                     \
        _Pragma("unroll") for (int i = 4; i < 8; ++i) ah[i] = rdA(ash, i);\
        if (STG) stageB(Bhi, Bsh[NXT], (KNXT));                            \
        SB0(); BAR(); LGKM0(); SB0();                                      \
        __builtin_amdgcn_s_setprio(1);                                     \
        MFMA16(ah, bh, 4);                                                 \
        __builtin_amdgcn_s_setprio(0);                                     \
        VMCNT(VM2); BAR();                                                 \
        /* -- P3 -- */                                                     \
        _Pragma("unroll") for (int i = 0; i < 4; ++i) bl[i] = rdB(bsl, i);\
        if (STG) stageA(Alo, Asl[NXT], (KNXT));                            \
        SB0(); BAR(); LGKM0(); SB0();                                      \
        __builtin_amdgcn_s_setprio(1);                                     \
        MFMA16(ah, bl, 0);                                                 \
        __builtin_amdgcn_s_setprio(0);                                     \
        BAR();                                                             \
        /* -- P4 -- */                                                     \
        if (STG) stageB(Blo, Bsl[NXT], (KNXT));                            \
        SB0(); BAR(); SB0();                                               \
        __builtin_amdgcn_s_setprio(1);                                     \
        MFMA16(ah, bl, 4);                                                 \
        __builtin_amdgcn_s_setprio(0);                                     \
        BAR();                                                             \
        /* -- P5 -- */                                                     \
        _Pragma("unroll") for (int i = 0; i < 4; ++i) al[i] = rdA(asl, i);\
        SB0(); BAR(); LGKM0(); SB0();                                      \
        __builtin_amdgcn_s_setprio(1);                                     \
        MFMA16(al, bh, 0);                                                 \
        __builtin_amdgcn_s_setprio(0);                                     \
        BAR();                                                             \
        /* -- P6 -- */                                                     \
        _Pragma("unroll") for (int i = 4; i < 8; ++i) al[i] = rdA(asl, i);\
        SB0(); BAR(); LGKM0(); SB0();                                      \
        __builtin_amdgcn_s_setprio(1);                                     \
        MFMA16(al, bh, 4);                                                 \
        __builtin_amdgcn_s_setprio(0);                                     \
        if (DOVM6) { VMCNT(4); }                                           \
        BAR();                                                             \
    }

    // prologue: stage tile 0 (8 loads: Ah,Bh,Al,Bl order), wait first 4
    stageA(Ahi, Ash[0], 0);
    stageB(Bhi, Bsh[0], 0);
    stageA(Alo, Asl[0], 0);
    stageB(Blo, Bsl[0], 0);
    VMCNT(4);
    BAR();

#pragma unroll 1
    for (int t2 = 0; t2 < 7; ++t2) {   // tiles 0..13
        const int kb = t2 * 2 * BK;
        TILE(0, 1, kb + BK, 1, 4, 1);
        TILE(1, 0, kb + 2 * BK, 1, 4, 1);
    }
    TILE(0, 1, 15 * BK, 1, 4, 1);      // tile 14, stages tile 15
    TILE(1, 0, 0, 0, 0, 0);            // tile 15: no stage, vmcnt(0) at P2

#undef TILE
#undef MFMA16

    // epilogue: sigmoid -> fp32, nontemporal (never re-read)
    const int ccol = lane & 15;
    const int crow = (lane >> 4) * 4;
#pragma unroll
    for (int mi = 0; mi < 8; ++mi) {
#pragma unroll
        for (int ni = 0; ni < 4; ++ni) {
#pragma unroll
            for (int r = 0; r < 4; ++r) {
                const size_t i = (size_t)(bm * BM + wm + mi * 16 + crow + r);
                const size_t j = (size_t)(bn * BM + wn + ni * 16 + ccol);
                const float v = acc[mi][ni][r];
                const float sv = 1.0f / (1.0f + __expf(-v));
                __builtin_nontemporal_store(sv, &Cf[i * M_ROWS + j]);
            }
        }
    }
}

extern "C" void kernel_launch(void* const* d_in, const int* in_sizes, int n_in,
                              void* d_out, int out_size, void* d_ws, size_t ws_size,
                              hipStream_t stream) {
    const float* x  = (const float*)d_in[0];
    const float* y  = (const float*)d_in[1];
    const float* mx = (const float*)d_in[2];
    const float* my = (const float*)d_in[3];
    const float* W  = (const float*)d_in[4];
    float* out = (float*)d_out;

    const size_t ND = (size_t)N_ROWS * DDIM;  // 4,194,304
    const size_t WD = (size_t)DDIM * DDIM;    // 262,144

    bf16_t* ws = (bf16_t*)d_ws;
    bf16_t* xd_hi = ws;
    bf16_t* xd_lo = ws + ND;
    bf16_t* yd_hi = ws + 2 * ND;
    bf16_t* yd_lo = ws + 3 * ND;
    bf16_t* xt_hi = ws + 4 * ND;
    bf16_t* xt_lo = ws + 5 * ND;
    bf16_t* W_hi  = ws + 6 * ND;
    bf16_t* W_lo  = ws + 6 * ND + WD;

    // fused prep: dropout + hi/lo split for x, y, W in one launch
    prep_all<<<4096 + 4096 + 256, 256, 0, stream>>>(
        x, mx, y, my, W, xd_hi, xd_lo, yd_hi, yd_lo, W_hi, W_lo);

    // GEMM1: xt[n,k] = sum_d xd[n,d]*W[k,d]  (8192x512), 64x64 tiles
    gemm_fused<0, 2, 2, 128, 8><<<128 * 8, 256, 0, stream>>>(
        xd_hi, xd_lo, W_hi, W_lo, nullptr, xt_hi, xt_lo, DDIM);

    // GEMM2: out = sigmoid(xt @ yd^T)  (8192x8192), 256x256 tiles, 1024 blocks
    gemm2_sig<<<1024, 512, 0, stream>>>(xt_hi, xt_lo, yd_hi, yd_lo, out);
}

// Round 3
// 457.548 us; speedup vs baseline: 1.1568x; 1.1158x over previous
//
#include <hip/hip_runtime.h>
#include <stdint.h>

// BilinearDiscriminator: out = sigmoid((x*mask_x) @ W^T @ (y*mask_y)^T)
// R6: PRECISION RESTRUCTURE. fp16 (2^-11 mantissa) instead of bf16 (2^-8):
//  - GEMM1 (xt = xd @ W^T): fp16 hi/lo for BOTH sides, 3 segments (hh+lh+hl)
//    -> xt accurate to ~22 bits, stored as fp16 hi/lo. Same work as before.
//  - GEMM2 (out = sigmoid(xt @ yd^T)): xt split (hi/lo), yd SINGLE fp16 plane.
//    2 segments (Th*Y + Tl*Y) instead of 3 -> -33% MFMA work, -17% LDS reads.
//    Error from yd quantization: sqrt(512)*2^-12*E|t*y| ~ 5.5e-3 logit -> <=1.4e-3
//    output (sigmoid slope <= 1/4). Risk: absmax may rise ~2x vs bf16-3seg.
// GEMM2 keeps the R5 phase-interleaved schedule refit to 4 phases x 16 MFMA,
// counted vmcnt(4)/vmcnt(2) per tile, vmcnt(0) only in peeled last tile.
// LDS drops 128 KiB -> 96 KiB (3 planes x dbuf).

typedef _Float16 f16_t;
typedef f16_t f16x8 __attribute__((ext_vector_type(8)));
typedef f16_t f16x4 __attribute__((ext_vector_type(4)));
typedef float f32x4 __attribute__((ext_vector_type(4)));

#define N_ROWS 8192
#define M_ROWS 8192
#define DDIM 512
#define BK 32

__device__ __forceinline__ void async_cp16(const f16_t* g, f16_t* l) {
    __builtin_amdgcn_global_load_lds(
        (const __attribute__((address_space(1))) unsigned int*)(uintptr_t)g,
        (__attribute__((address_space(3))) unsigned int*)(uint32_t)(uintptr_t)l,
        16, 0, 0);
}

#define VMCNT_(n) asm volatile("s_waitcnt vmcnt(" #n ")" ::: "memory")
#define VMCNT(n) VMCNT_(n)
#define LGKM0()  asm volatile("s_waitcnt lgkmcnt(0)" ::: "memory")
#define SB0()    __builtin_amdgcn_sched_barrier(0)
#define BAR()    __builtin_amdgcn_s_barrier()

// One kernel for all three dropout+split preps.
// blocks [0,4096): x -> hi/lo   [4096,8192): y -> single   [8192,8448): W -> hi/lo
__global__ __launch_bounds__(256) void prep_all(
    const float* __restrict__ x, const float* __restrict__ mx,
    const float* __restrict__ y, const float* __restrict__ my,
    const float* __restrict__ W,
    f16_t* __restrict__ xd_hi, f16_t* __restrict__ xd_lo,
    f16_t* __restrict__ yd,
    f16_t* __restrict__ W_hi, f16_t* __restrict__ W_lo) {
    const int b = blockIdx.x;
    const float* v; const float* m; f16_t* hi; f16_t* lo; int idx;
    if (b < 4096)      { v = x; m = mx;      hi = xd_hi; lo = xd_lo; idx = b * 256 + threadIdx.x; }
    else if (b < 8192) { v = y; m = my;      hi = yd;    lo = nullptr; idx = (b - 4096) * 256 + threadIdx.x; }
    else               { v = W; m = nullptr; hi = W_hi;  lo = W_lo;  idx = (b - 8192) * 256 + threadIdx.x; }
    float4 xv = ((const float4*)v)[idx];
    if (m) {
        float4 mv = ((const float4*)m)[idx];
        xv.x *= mv.x; xv.y *= mv.y; xv.z *= mv.z; xv.w *= mv.w;
    }
    float vals[4] = {xv.x, xv.y, xv.z, xv.w};
    f16x4 h, l;
#pragma unroll
    for (int i = 0; i < 4; ++i) {
        f16_t hh = (f16_t)vals[i];
        h[i] = hh;
        l[i] = (f16_t)(vals[i] - (float)hh);
    }
    *(f16x4*)(hi + (size_t)idx * 4) = h;
    if (lo) *(f16x4*)(lo + (size_t)idx * 4) = l;
}

// ---------------------------------------------------------------------------
// GEMM1 (64x64 tiles, old 2-barrier structure): xt = xd @ W^T, fp16 hi/lo on
// BOTH sides, 3 segments (hh + lh + hl) -> xt good to ~22 bits. Epilogue
// writes xt as fp16 hi/lo. Small kernel (1/16 of GEMM2's FLOPs).
// ---------------------------------------------------------------------------
template <int MI, int NI, int TM, int TN>
__global__ __launch_bounds__(256) void gemm1_split(
    const f16_t* __restrict__ Ahi, const f16_t* __restrict__ Alo,
    const f16_t* __restrict__ Bhi, const f16_t* __restrict__ Blo,
    f16_t* __restrict__ Chi, f16_t* __restrict__ Clo,
    int ldc) {
    constexpr int BM = MI * 32;
    constexpr int BN = NI * 32;
    constexpr int AS = BM * 4 / 256;
    constexpr int BS = BN * 4 / 256;
    constexpr int SN = TN / 8;

    __shared__ __align__(16) f16_t Ash[BM * BK];
    __shared__ __align__(16) f16_t Asl[BM * BK];
    __shared__ __align__(16) f16_t Bsh[BN * BK];
    __shared__ __align__(16) f16_t Bsl[BN * BK];

    const int tid = threadIdx.x;
    const int lane = tid & 63;
    const int wave = tid >> 6;
    const int wm = (wave & 1) * MI * 16;
    const int wn = (wave >> 1) * NI * 16;

    const int bid = blockIdx.x;
    const int jj = bid & 7;
    const int ii = (bid >> 3) & 7;
    const int sc = (bid >> 6) % SN;
    const int sr = (bid >> 6) / SN;
    const int bm = sr * 8 + ii;
    const int bn = sc * 8 + jj;

    const int m0 = lane & 15;
    const int kc = lane >> 4;
    const int fsw = kc ^ ((m0 >> 1) & 3);

    f32x4 acc[MI][NI];
#pragma unroll
    for (int i = 0; i < MI; ++i)
#pragma unroll
        for (int j = 0; j < NI; ++j)
            acc[i][j] = (f32x4){0.f, 0.f, 0.f, 0.f};

    for (int k0 = 0; k0 < DDIM; k0 += BK) {
        __syncthreads();
#pragma unroll
        for (int s = 0; s < AS; ++s) {
            const int slot = tid + s * 256;
            const int r = slot >> 2;
            const int c = (slot & 3) ^ ((r >> 1) & 3);
            const size_t g = (size_t)(bm * BM + r) * DDIM + k0 + c * 8;
            async_cp16(Ahi + g, &Ash[slot * 8]);
            async_cp16(Alo + g, &Asl[slot * 8]);
        }
#pragma unroll
        for (int s = 0; s < BS; ++s) {
            const int slot = tid + s * 256;
            const int r = slot >> 2;
            const int c = (slot & 3) ^ ((r >> 1) & 3);
            const size_t g = (size_t)(bn * BN + r) * DDIM + k0 + c * 8;
            async_cp16(Bhi + g, &Bsh[slot * 8]);
            async_cp16(Blo + g, &Bsl[slot * 8]);
        }
        __syncthreads();

        f16x8 ah[MI], bh[NI];
#pragma unroll
        for (int mi = 0; mi < MI; ++mi)
            ah[mi] = *(const f16x8*)&Ash[((wm + mi * 16 + m0) * 4 + fsw) * 8];
#pragma unroll
        for (int ni = 0; ni < NI; ++ni)
            bh[ni] = *(const f16x8*)&Bsh[((wn + ni * 16 + m0) * 4 + fsw) * 8];

#pragma unroll
        for (int mi = 0; mi < MI; ++mi)
#pragma unroll
            for (int ni = 0; ni < NI; ++ni)
                acc[mi][ni] = __builtin_amdgcn_mfma_f32_16x16x32_f16(
                    ah[mi], bh[ni], acc[mi][ni], 0, 0, 0);
        {
            f16x8 al[MI];
#pragma unroll
            for (int mi = 0; mi < MI; ++mi)
                al[mi] = *(const f16x8*)&Asl[((wm + mi * 16 + m0) * 4 + fsw) * 8];
#pragma unroll
            for (int mi = 0; mi < MI; ++mi)
#pragma unroll
                for (int ni = 0; ni < NI; ++ni)
                    acc[mi][ni] = __builtin_amdgcn_mfma_f32_16x16x32_f16(
                        al[mi], bh[ni], acc[mi][ni], 0, 0, 0);
        }
        {
            f16x8 bl[NI];
#pragma unroll
            for (int ni = 0; ni < NI; ++ni)
                bl[ni] = *(const f16x8*)&Bsl[((wn + ni * 16 + m0) * 4 + fsw) * 8];
#pragma unroll
            for (int mi = 0; mi < MI; ++mi)
#pragma unroll
                for (int ni = 0; ni < NI; ++ni)
                    acc[mi][ni] = __builtin_amdgcn_mfma_f32_16x16x32_f16(
                        ah[mi], bl[ni], acc[mi][ni], 0, 0, 0);
        }
    }

    const int ccol = lane & 15;
    const int crow = (lane >> 4) * 4;
#pragma unroll
    for (int mi = 0; mi < MI; ++mi) {
#pragma unroll
        for (int ni = 0; ni < NI; ++ni) {
#pragma unroll
            for (int r = 0; r < 4; ++r) {
                const int i = bm * BM + wm + mi * 16 + crow + r;
                const int j = bn * BN + wn + ni * 16 + ccol;
                const float v = acc[mi][ni][r];
                f16_t h = (f16_t)v;
                f16_t lo = (f16_t)(v - (float)h);
                Chi[(size_t)i * ldc + j] = h;
                Clo[(size_t)i * ldc + j] = lo;
            }
        }
    }
}

// ---------------------------------------------------------------------------
// GEMM2: out = sigmoid(xt @ yd^T), 8192x8192, K=512. 256x256 tile, 8 waves
// (2Mx4N), per-wave 128x64 output. A = xt (fp16 hi/lo), B = yd (fp16 single).
// 2 segments -> 64 MFMA per BK=32 tile per wave, 20 ds_read_b128.
// LDS 96 KiB: Ash/Asl/Bsh x dbuf. 4 phases per K-tile, 16 MFMA each:
//   P1: rd ah[0..3], b[0..3] | stage Ah(t+1) | hh-lo (ah03 x b)
//   P2: rd ah[4..7]          | stage B (t+1) | hh-hi (ah47 x b)   [vmcnt(4)]
//   P3: rd al[0..3]          | stage Al(t+1) | lh-lo (al03 x b)
//   P4: rd al[4..7]          |               | lh-hi (al47 x b)   [vmcnt(2)]
// Counted-wait trace (per-wave outstanding): entry=Al_t(2); P1 +Ah_{t+1};
// P2 +B_{t+1} -> 6; vmcnt(4) drains Al_t before P3 reads it. P3 +Al_{t+1};
// end-P4 vmcnt(2) drains Ah/B_{t+1} before next tile's P1 reads. vmcnt(0)
// only in peeled tile 15. Stage-vs-read hazard on the NXT buffer is closed
// by each phase's second barrier (readers' lgkm0 precedes their arrival).
// ---------------------------------------------------------------------------
__global__ __launch_bounds__(512, 2) void gemm2_sig(
    const f16_t* __restrict__ Ahi, const f16_t* __restrict__ Alo,
    const f16_t* __restrict__ Bh,
    float* __restrict__ Cf) {
    constexpr int BM = 256;           // = BN
    constexpr int LDT = BM * BK;      // 8192 f16 = 16 KiB per plane per buf

    __shared__ __align__(16) f16_t Ash[2][LDT];
    __shared__ __align__(16) f16_t Asl[2][LDT];
    __shared__ __align__(16) f16_t Bsh[2][LDT];

    const int tid = threadIdx.x;
    const int lane = tid & 63;
    const int wave = tid >> 6;
    const int wm = (wave >> 2) * 128;   // wave-row: 0 / 128
    const int wn = (wave & 3) * 64;     // wave-col: 0 / 64 / 128 / 192

    // supertile order (32x32 tile grid, 1024 blocks): bn fastest -> XCD id
    const int bid = blockIdx.x;
    const int jj = bid & 7;
    const int ii = (bid >> 3) & 7;
    const int sc = (bid >> 6) & 3;
    const int sr = (bid >> 6) >> 2;
    const int bm = sr * 8 + ii;
    const int bn = sc * 8 + jj;

    const int m0 = lane & 15;
    const int kc = lane >> 4;
    const int fsw = kc ^ ((m0 >> 1) & 3);  // swizzled chunk for fragment reads

    // per-thread staging map: 2 16B slots per plane per K-tile (1024 slots)
    int aOff[2], bOff[2], lofs[2];
#pragma unroll
    for (int s = 0; s < 2; ++s) {
        const int slot = tid + s * 512;
        const int r = slot >> 2;
        const int c = (slot & 3) ^ ((r >> 1) & 3);  // pre-swizzled global src
        aOff[s] = (bm * BM + r) * DDIM + c * 8;
        bOff[s] = (bn * BM + r) * DDIM + c * 8;
        lofs[s] = slot * 8;
    }

    f32x4 acc[8][4];
#pragma unroll
    for (int i = 0; i < 8; ++i)
#pragma unroll
        for (int j = 0; j < 4; ++j) acc[i][j] = (f32x4){0.f, 0.f, 0.f, 0.f};

    auto stageA = [&](const f16_t* g, f16_t* l, int k0) {
#pragma unroll
        for (int s = 0; s < 2; ++s) async_cp16(g + aOff[s] + k0, l + lofs[s]);
    };
    auto stageB = [&](const f16_t* g, f16_t* l, int k0) {
#pragma unroll
        for (int s = 0; s < 2; ++s) async_cp16(g + bOff[s] + k0, l + lofs[s]);
    };
    auto rdA = [&](const f16_t* s, int mi) {
        return *(const f16x8*)&s[((wm + mi * 16 + m0) * 4 + fsw) * 8];
    };
    auto rdB = [&](const f16_t* s, int ni) {
        return *(const f16x8*)&s[((wn + ni * 16 + m0) * 4 + fsw) * 8];
    };

    f16x8 ah[8], al[8], b[4];

#define MFMA16(AA, MI0)                                                   \
    _Pragma("unroll") for (int mi = 0; mi < 4; ++mi)                      \
    _Pragma("unroll") for (int ni = 0; ni < 4; ++ni)                      \
        acc[(MI0) + mi][ni] = __builtin_amdgcn_mfma_f32_16x16x32_f16(     \
            AA[(MI0) + mi], b[ni], acc[(MI0) + mi][ni], 0, 0, 0);

#define TILE(CUR, NXT, KNXT, STG, VM1, DOVM2)                             \
    {                                                                      \
        const f16_t* ash = Ash[CUR]; const f16_t* asl = Asl[CUR];         \
        const f16_t* bsh = Bsh[CUR];                                       \
        /* -- P1 -- */                                                     \
        _Pragma("unroll") for (int i = 0; i < 4; ++i) ah[i] = rdA(ash, i);\
        _Pragma("unroll") for (int i = 0; i < 4; ++i) b[i] = rdB(bsh, i); \
        if (STG) stageA(Ahi, Ash[NXT], (KNXT));                            \
        SB0(); BAR(); LGKM0(); SB0();                                      \
        __builtin_amdgcn_s_setprio(1);                                     \
        MFMA16(ah, 0);                                                     \
        __builtin_amdgcn_s_setprio(0);                                     \
        BAR();                                                             \
        /* -- P2 -- */                                                     \
        _Pragma("unroll") for (int i = 4; i < 8; ++i) ah[i] = rdA(ash, i);\
        if (STG) stageB(Bh, Bsh[NXT], (KNXT));                             \
        SB0(); BAR(); LGKM0(); SB0();                                      \
        __builtin_amdgcn_s_setprio(1);                                     \
        MFMA16(ah, 4);                                                     \
        __builtin_amdgcn_s_setprio(0);                                     \
        VMCNT(VM1); BAR();                                                 \
        /* -- P3 -- */                                                     \
        _Pragma("unroll") for (int i = 0; i < 4; ++i) al[i] = rdA(asl, i);\
        if (STG) stageA(Alo, Asl[NXT], (KNXT));                            \
        SB0(); BAR(); LGKM0(); SB0();                                      \
        __builtin_amdgcn_s_setprio(1);                                     \
        MFMA16(al, 0);                                                     \
        __builtin_amdgcn_s_setprio(0);                                     \
        BAR();                                                             \
        /* -- P4 -- */                                                     \
        _Pragma("unroll") for (int i = 4; i < 8; ++i) al[i] = rdA(asl, i);\
        SB0(); BAR(); LGKM0(); SB0();                                      \
        __builtin_amdgcn_s_setprio(1);                                     \
        MFMA16(al, 4);                                                     \
        __builtin_amdgcn_s_setprio(0);                                     \
        if (DOVM2) { VMCNT(2); }                                           \
        BAR();                                                             \
    }

    // prologue: stage tile 0 (Ah, B, Al = 6 loads); need Ah,B before P1
    stageA(Ahi, Ash[0], 0);
    stageB(Bh, Bsh[0], 0);
    stageA(Alo, Asl[0], 0);
    VMCNT(2);
    BAR();

#pragma unroll 1
    for (int t2 = 0; t2 < 7; ++t2) {   // tiles 0..13
        const int kb = t2 * 2 * BK;
        TILE(0, 1, kb + BK, 1, 4, 1);
        TILE(1, 0, kb + 2 * BK, 1, 4, 1);
    }
    TILE(0, 1, 15 * BK, 1, 4, 1);      // tile 14, stages tile 15
    TILE(1, 0, 0, 0, 0, 0);            // tile 15: no stage, vmcnt(0) at P2

#undef TILE
#undef MFMA16

    // epilogue: sigmoid -> fp32, nontemporal (never re-read)
    const int ccol = lane & 15;
    const int crow = (lane >> 4) * 4;
#pragma unroll
    for (int mi = 0; mi < 8; ++mi) {
#pragma unroll
        for (int ni = 0; ni < 4; ++ni) {
#pragma unroll
            for (int r = 0; r < 4; ++r) {
                const size_t i = (size_t)(bm * BM + wm + mi * 16 + crow + r);
                const size_t j = (size_t)(bn * BM + wn + ni * 16 + ccol);
                const float v = acc[mi][ni][r];
                const float sv = 1.0f / (1.0f + __expf(-v));
                __builtin_nontemporal_store(sv, &Cf[i * M_ROWS + j]);
            }
        }
    }
}

extern "C" void kernel_launch(void* const* d_in, const int* in_sizes, int n_in,
                              void* d_out, int out_size, void* d_ws, size_t ws_size,
                              hipStream_t stream) {
    const float* x  = (const float*)d_in[0];
    const float* y  = (const float*)d_in[1];
    const float* mx = (const float*)d_in[2];
    const float* my = (const float*)d_in[3];
    const float* W  = (const float*)d_in[4];
    float* out = (float*)d_out;

    const size_t ND = (size_t)N_ROWS * DDIM;  // 4,194,304
    const size_t WD = (size_t)DDIM * DDIM;    // 262,144

    f16_t* ws = (f16_t*)d_ws;
    f16_t* xd_hi = ws;
    f16_t* xd_lo = ws + ND;
    f16_t* yd    = ws + 2 * ND;
    f16_t* xt_hi = ws + 3 * ND;
    f16_t* xt_lo = ws + 4 * ND;
    f16_t* W_hi  = ws + 5 * ND;
    f16_t* W_lo  = ws + 5 * ND + WD;

    // fused prep: dropout + fp16 splits (x, W) and fp16 cast (y)
    prep_all<<<4096 + 4096 + 256, 256, 0, stream>>>(
        x, mx, y, my, W, xd_hi, xd_lo, yd, W_hi, W_lo);

    // GEMM1: xt = xd @ W^T (8192x512), fp16 3-segment, 64x64 tiles
    gemm1_split<2, 2, 128, 8><<<128 * 8, 256, 0, stream>>>(
        xd_hi, xd_lo, W_hi, W_lo, xt_hi, xt_lo, DDIM);

    // GEMM2: out = sigmoid(xt @ yd^T), fp16 2-segment, 256x256 tiles
    gemm2_sig<<<1024, 512, 0, stream>>>(xt_hi, xt_lo, yd, out);
}

// Round 4
// 457.325 us; speedup vs baseline: 1.1574x; 1.0005x over previous
//
#include <hip/hip_runtime.h>
#include <stdint.h>

// BilinearDiscriminator: out = sigmoid((x*mask_x) @ W^T @ (y*mask_y)^T)
// fp16 asymmetric precision (R6, verified absmax 0.0078):
//   GEMM1: xt = xd @ W^T, fp16 hi/lo both sides, 3 segments -> xt ~22-bit.
//   GEMM2: xt (hi/lo) @ yd (single fp16 plane), 2 segments.
// R7: OCCUPANCY. GEMM2 was 1 block/CU (LDS 96 KiB) -> barrier/LDS phases had
// no co-resident block to overlap with (MfmaUtil 34%). Shrink LDS to 64 KiB:
//   Ash (xt_hi) double-buffered; Bsh (yd) single (read only in P1, restaged
//   at P2 after P1-close); Asl (xt_lo) single (read P3/P4, restaged after
//   P4-close). 128V+128A per wave + 64 KiB -> 2 blocks/CU: cross-block
//   overlap fills the lockstep gaps (m114 mechanism) on top of counted vmcnt.
// Wait trace (per-wave FIFO): start of tile t: [Alo(t)x2]. P1 +Ah(t+1).
// P2 +B(t+1) -> 6; vmcnt(4) drains Alo(t) before P3 reads it. P4 vmcnt(0)
// drains Ah/B(t+1) (issued 2-3 phases back, ~free) before next P1; then
// barrier, then stage Alo(t+1) into the just-freed Asl.

typedef _Float16 f16_t;
typedef f16_t f16x8 __attribute__((ext_vector_type(8)));
typedef f16_t f16x4 __attribute__((ext_vector_type(4)));
typedef float f32x4 __attribute__((ext_vector_type(4)));

#define N_ROWS 8192
#define M_ROWS 8192
#define DDIM 512
#define BK 32

__device__ __forceinline__ void async_cp16(const f16_t* g, f16_t* l) {
    __builtin_amdgcn_global_load_lds(
        (const __attribute__((address_space(1))) unsigned int*)(uintptr_t)g,
        (__attribute__((address_space(3))) unsigned int*)(uint32_t)(uintptr_t)l,
        16, 0, 0);
}

#define VMCNT_(n) asm volatile("s_waitcnt vmcnt(" #n ")" ::: "memory")
#define VMCNT(n) VMCNT_(n)
#define LGKM0()  asm volatile("s_waitcnt lgkmcnt(0)" ::: "memory")
#define SB0()    __builtin_amdgcn_sched_barrier(0)
#define BAR()    __builtin_amdgcn_s_barrier()

// One kernel for all three dropout+split preps.
// blocks [0,4096): x -> hi/lo   [4096,8192): y -> single   [8192,8448): W -> hi/lo
__global__ __launch_bounds__(256) void prep_all(
    const float* __restrict__ x, const float* __restrict__ mx,
    const float* __restrict__ y, const float* __restrict__ my,
    const float* __restrict__ W,
    f16_t* __restrict__ xd_hi, f16_t* __restrict__ xd_lo,
    f16_t* __restrict__ yd,
    f16_t* __restrict__ W_hi, f16_t* __restrict__ W_lo) {
    const int b = blockIdx.x;
    const float* v; const float* m; f16_t* hi; f16_t* lo; int idx;
    if (b < 4096)      { v = x; m = mx;      hi = xd_hi; lo = xd_lo; idx = b * 256 + threadIdx.x; }
    else if (b < 8192) { v = y; m = my;      hi = yd;    lo = nullptr; idx = (b - 4096) * 256 + threadIdx.x; }
    else               { v = W; m = nullptr; hi = W_hi;  lo = W_lo;  idx = (b - 8192) * 256 + threadIdx.x; }
    float4 xv = ((const float4*)v)[idx];
    if (m) {
        float4 mv = ((const float4*)m)[idx];
        xv.x *= mv.x; xv.y *= mv.y; xv.z *= mv.z; xv.w *= mv.w;
    }
    float vals[4] = {xv.x, xv.y, xv.z, xv.w};
    f16x4 h, l;
#pragma unroll
    for (int i = 0; i < 4; ++i) {
        f16_t hh = (f16_t)vals[i];
        h[i] = hh;
        l[i] = (f16_t)(vals[i] - (float)hh);
    }
    *(f16x4*)(hi + (size_t)idx * 4) = h;
    if (lo) *(f16x4*)(lo + (size_t)idx * 4) = l;
}

// ---------------------------------------------------------------------------
// GEMM1 (64x64 tiles, old 2-barrier structure): xt = xd @ W^T, fp16 hi/lo on
// BOTH sides, 3 segments (hh + lh + hl) -> xt good to ~22 bits. Epilogue
// writes xt as fp16 hi/lo. Small kernel (1/16 of GEMM2's FLOPs).
// ---------------------------------------------------------------------------
template <int MI, int NI, int TM, int TN>
__global__ __launch_bounds__(256) void gemm1_split(
    const f16_t* __restrict__ Ahi, const f16_t* __restrict__ Alo,
    const f16_t* __restrict__ Bhi, const f16_t* __restrict__ Blo,
    f16_t* __restrict__ Chi, f16_t* __restrict__ Clo,
    int ldc) {
    constexpr int BM = MI * 32;
    constexpr int BN = NI * 32;
    constexpr int AS = BM * 4 / 256;
    constexpr int BS = BN * 4 / 256;
    constexpr int SN = TN / 8;

    __shared__ __align__(16) f16_t Ash[BM * BK];
    __shared__ __align__(16) f16_t Asl[BM * BK];
    __shared__ __align__(16) f16_t Bsh[BN * BK];
    __shared__ __align__(16) f16_t Bsl[BN * BK];

    const int tid = threadIdx.x;
    const int lane = tid & 63;
    const int wave = tid >> 6;
    const int wm = (wave & 1) * MI * 16;
    const int wn = (wave >> 1) * NI * 16;

    const int bid = blockIdx.x;
    const int jj = bid & 7;
    const int ii = (bid >> 3) & 7;
    const int sc = (bid >> 6) % SN;
    const int sr = (bid >> 6) / SN;
    const int bm = sr * 8 + ii;
    const int bn = sc * 8 + jj;

    const int m0 = lane & 15;
    const int kc = lane >> 4;
    const int fsw = kc ^ ((m0 >> 1) & 3);

    f32x4 acc[MI][NI];
#pragma unroll
    for (int i = 0; i < MI; ++i)
#pragma unroll
        for (int j = 0; j < NI; ++j)
            acc[i][j] = (f32x4){0.f, 0.f, 0.f, 0.f};

    for (int k0 = 0; k0 < DDIM; k0 += BK) {
        __syncthreads();
#pragma unroll
        for (int s = 0; s < AS; ++s) {
            const int slot = tid + s * 256;
            const int r = slot >> 2;
            const int c = (slot & 3) ^ ((r >> 1) & 3);
            const size_t g = (size_t)(bm * BM + r) * DDIM + k0 + c * 8;
            async_cp16(Ahi + g, &Ash[slot * 8]);
            async_cp16(Alo + g, &Asl[slot * 8]);
        }
#pragma unroll
        for (int s = 0; s < BS; ++s) {
            const int slot = tid + s * 256;
            const int r = slot >> 2;
            const int c = (slot & 3) ^ ((r >> 1) & 3);
            const size_t g = (size_t)(bn * BN + r) * DDIM + k0 + c * 8;
            async_cp16(Bhi + g, &Bsh[slot * 8]);
            async_cp16(Blo + g, &Bsl[slot * 8]);
        }
        __syncthreads();

        f16x8 ah[MI], bh[NI];
#pragma unroll
        for (int mi = 0; mi < MI; ++mi)
            ah[mi] = *(const f16x8*)&Ash[((wm + mi * 16 + m0) * 4 + fsw) * 8];
#pragma unroll
        for (int ni = 0; ni < NI; ++ni)
            bh[ni] = *(const f16x8*)&Bsh[((wn + ni * 16 + m0) * 4 + fsw) * 8];

#pragma unroll
        for (int mi = 0; mi < MI; ++mi)
#pragma unroll
            for (int ni = 0; ni < NI; ++ni)
                acc[mi][ni] = __builtin_amdgcn_mfma_f32_16x16x32_f16(
                    ah[mi], bh[ni], acc[mi][ni], 0, 0, 0);
        {
            f16x8 al[MI];
#pragma unroll
            for (int mi = 0; mi < MI; ++mi)
                al[mi] = *(const f16x8*)&Asl[((wm + mi * 16 + m0) * 4 + fsw) * 8];
#pragma unroll
            for (int mi = 0; mi < MI; ++mi)
#pragma unroll
                for (int ni = 0; ni < NI; ++ni)
                    acc[mi][ni] = __builtin_amdgcn_mfma_f32_16x16x32_f16(
                        al[mi], bh[ni], acc[mi][ni], 0, 0, 0);
        }
        {
            f16x8 bl[NI];
#pragma unroll
            for (int ni = 0; ni < NI; ++ni)
                bl[ni] = *(const f16x8*)&Bsl[((wn + ni * 16 + m0) * 4 + fsw) * 8];
#pragma unroll
            for (int mi = 0; mi < MI; ++mi)
#pragma unroll
                for (int ni = 0; ni < NI; ++ni)
                    acc[mi][ni] = __builtin_amdgcn_mfma_f32_16x16x32_f16(
                        ah[mi], bl[ni], acc[mi][ni], 0, 0, 0);
        }
    }

    const int ccol = lane & 15;
    const int crow = (lane >> 4) * 4;
#pragma unroll
    for (int mi = 0; mi < MI; ++mi) {
#pragma unroll
        for (int ni = 0; ni < NI; ++ni) {
#pragma unroll
            for (int r = 0; r < 4; ++r) {
                const int i = bm * BM + wm + mi * 16 + crow + r;
                const int j = bn * BN + wn + ni * 16 + ccol;
                const float v = acc[mi][ni][r];
                f16_t h = (f16_t)v;
                f16_t lo = (f16_t)(v - (float)h);
                Chi[(size_t)i * ldc + j] = h;
                Clo[(size_t)i * ldc + j] = lo;
            }
        }
    }
}

// ---------------------------------------------------------------------------
// GEMM2: out = sigmoid(xt @ yd^T), 8192x8192, K=512. 256x256 tile, 8 waves
// (2Mx4N), per-wave 128x64 output. A = xt (fp16 hi/lo), B = yd (fp16 single).
// LDS 64 KiB -> 2 blocks/CU: Ash dbuf (2x16K), Bsh single (16K, read only in
// P1, restaged at P2 after P1-close), Asl single (16K, read P3/P4, restaged
// after P4-close). 4 phases x 16 MFMA per K-tile:
//   P1: rd ah[0..3], b[0..3] | stage Ah(t+1)->Ash[nxt] | hh-lo
//   P2: rd ah[4..7]          | stage B (t+1)->Bsh      | hh-hi  [vmcnt(4)]
//   P3: rd al[0..3]          |                         | lh-lo
//   P4: rd al[4..7]          |                         | lh-hi  [vmcnt(0)]
//        ... BAR, then stage Alo(t+1)->Asl (single buf, just freed).
// vmcnt(0) at P4 drains loads issued 2-3 phases (~3000 cyc) earlier -> ~free.
// Single-buffer safety: B(t+1) staged after P1-close (all b-reads done);
// Alo(t+1) staged after P4-close (all al-reads done); arrival gated by the
// next tile's vmcnt(4)/(0) + barrier before the dependent ds_reads.
// ---------------------------------------------------------------------------
__global__ __launch_bounds__(512, 2) void gemm2_sig(
    const f16_t* __restrict__ Ahi, const f16_t* __restrict__ Alo,
    const f16_t* __restrict__ Bh,
    float* __restrict__ Cf) {
    constexpr int BM = 256;           // = BN
    constexpr int LDT = BM * BK;      // 8192 f16 = 16 KiB per plane per buf

    __shared__ __align__(16) f16_t Ash[2][LDT];  // xt_hi, double-buffered
    __shared__ __align__(16) f16_t Asl[LDT];     // xt_lo, single buffer
    __shared__ __align__(16) f16_t Bsh[LDT];     // yd, single buffer

    const int tid = threadIdx.x;
    const int lane = tid & 63;
    const int wave = tid >> 6;
    const int wm = (wave >> 2) * 128;   // wave-row: 0 / 128
    const int wn = (wave & 3) * 64;     // wave-col: 0 / 64 / 128 / 192

    // supertile order (32x32 tile grid, 1024 blocks): bn fastest -> XCD id
    const int bid = blockIdx.x;
    const int jj = bid & 7;
    const int ii = (bid >> 3) & 7;
    const int sc = (bid >> 6) & 3;
    const int sr = (bid >> 6) >> 2;
    const int bm = sr * 8 + ii;
    const int bn = sc * 8 + jj;

    const int m0 = lane & 15;
    const int kc = lane >> 4;
    const int fsw = kc ^ ((m0 >> 1) & 3);  // swizzled chunk for fragment reads

    // per-thread staging map: 2 16B slots per plane per K-tile (1024 slots)
    int aOff[2], bOff[2], lofs[2];
#pragma unroll
    for (int s = 0; s < 2; ++s) {
        const int slot = tid + s * 512;
        const int r = slot >> 2;
        const int c = (slot & 3) ^ ((r >> 1) & 3);  // pre-swizzled global src
        aOff[s] = (bm * BM + r) * DDIM + c * 8;
        bOff[s] = (bn * BM + r) * DDIM + c * 8;
        lofs[s] = slot * 8;
    }

    f32x4 acc[8][4];
#pragma unroll
    for (int i = 0; i < 8; ++i)
#pragma unroll
        for (int j = 0; j < 4; ++j) acc[i][j] = (f32x4){0.f, 0.f, 0.f, 0.f};

    auto stageA = [&](const f16_t* g, f16_t* l, int k0) {
#pragma unroll
        for (int s = 0; s < 2; ++s) async_cp16(g + aOff[s] + k0, l + lofs[s]);
    };
    auto stageB = [&](const f16_t* g, f16_t* l, int k0) {
#pragma unroll
        for (int s = 0; s < 2; ++s) async_cp16(g + bOff[s] + k0, l + lofs[s]);
    };
    auto rdA = [&](const f16_t* s, int mi) {
        return *(const f16x8*)&s[((wm + mi * 16 + m0) * 4 + fsw) * 8];
    };
    auto rdB = [&](const f16_t* s, int ni) {
        return *(const f16x8*)&s[((wn + ni * 16 + m0) * 4 + fsw) * 8];
    };

    f16x8 ah[8], al[8], b[4];

#define MFMA16(AA, MI0)                                                   \
    _Pragma("unroll") for (int mi = 0; mi < 4; ++mi)                      \
    _Pragma("unroll") for (int ni = 0; ni < 4; ++ni)                      \
        acc[(MI0) + mi][ni] = __builtin_amdgcn_mfma_f32_16x16x32_f16(     \
            AA[(MI0) + mi], b[ni], acc[(MI0) + mi][ni], 0, 0, 0);

#define TILE(CUR, NXT, KNXT, STG, VM1, DOVM4)                             \
    {                                                                      \
        const f16_t* ash = Ash[CUR];                                       \
        /* -- P1 -- */                                                     \
        _Pragma("unroll") for (int i = 0; i < 4; ++i) ah[i] = rdA(ash, i);\
        _Pragma("unroll") for (int i = 0; i < 4; ++i) b[i] = rdB(Bsh, i); \
        if (STG) stageA(Ahi, Ash[NXT], (KNXT));                            \
        SB0(); BAR(); LGKM0(); SB0();                                      \
        __builtin_amdgcn_s_setprio(1);                                     \
        MFMA16(ah, 0);                                                     \
        __builtin_amdgcn_s_setprio(0);                                     \
        BAR();                                                             \
        /* -- P2 -- */                                                     \
        _Pragma("unroll") for (int i = 4; i < 8; ++i) ah[i] = rdA(ash, i);\
        if (STG) stageB(Bh, Bsh, (KNXT));                                  \
        SB0(); BAR(); LGKM0(); SB0();                                      \
        __builtin_amdgcn_s_setprio(1);                                     \
        MFMA16(ah, 4);                                                     \
        __builtin_amdgcn_s_setprio(0);                                     \
        VMCNT(VM1); BAR();                                                 \
        /* -- P3 -- */                                                     \
        _Pragma("unroll") for (int i = 0; i < 4; ++i) al[i] = rdA(Asl, i);\
        SB0(); BAR(); LGKM0(); SB0();                                      \
        __builtin_amdgcn_s_setprio(1);                                     \
        MFMA16(al, 0);                                                     \
        __builtin_amdgcn_s_setprio(0);                                     \
        BAR();                                                             \
        /* -- P4 -- */                                                     \
        _Pragma("unroll") for (int i = 4; i < 8; ++i) al[i] = rdA(Asl, i);\
        SB0(); BAR(); LGKM0(); SB0();                                      \
        __builtin_amdgcn_s_setprio(1);                                     \
        MFMA16(al, 4);                                                     \
        __builtin_amdgcn_s_setprio(0);                                     \
        if (DOVM4) { VMCNT(0); }                                           \
        BAR();                                                             \
        if (STG) stageA(Alo, Asl, (KNXT));                                 \
    }

    // prologue: stage tile 0 (Ah, B, Alo = 6 loads); P1 needs Ah,B only
    stageA(Ahi, Ash[0], 0);
    stageB(Bh, Bsh, 0);
    stageA(Alo, Asl, 0);
    VMCNT(2);
    BAR();

#pragma unroll 1
    for (int t2 = 0; t2 < 7; ++t2) {   // tiles 0..13
        const int kb = t2 * 2 * BK;
        TILE(0, 1, kb + BK, 1, 4, 1);
        TILE(1, 0, kb + 2 * BK, 1, 4, 1);
    }
    TILE(0, 1, 15 * BK, 1, 4, 1);      // tile 14, stages tile 15 (Ah,B,Alo)
    TILE(1, 0, 0, 0, 0, 0);            // tile 15: no stage, vmcnt(0) at P2

#undef TILE
#undef MFMA16

    // epilogue: sigmoid -> fp32, nontemporal (never re-read)
    const int ccol = lane & 15;
    const int crow = (lane >> 4) * 4;
#pragma unroll
    for (int mi = 0; mi < 8; ++mi) {
#pragma unroll
        for (int ni = 0; ni < 4; ++ni) {
#pragma unroll
            for (int r = 0; r < 4; ++r) {
                const size_t i = (size_t)(bm * BM + wm + mi * 16 + crow + r);
                const size_t j = (size_t)(bn * BM + wn + ni * 16 + ccol);
                const float v = acc[mi][ni][r];
                const float sv = 1.0f / (1.0f + __expf(-v));
                __builtin_nontemporal_store(sv, &Cf[i * M_ROWS + j]);
            }
        }
    }
}

extern "C" void kernel_launch(void* const* d_in, const int* in_sizes, int n_in,
                              void* d_out, int out_size, void* d_ws, size_t ws_size,
                              hipStream_t stream) {
    const float* x  = (const float*)d_in[0];
    const float* y  = (const float*)d_in[1];
    const float* mx = (const float*)d_in[2];
    const float* my = (const float*)d_in[3];
    const float* W  = (const float*)d_in[4];
    float* out = (float*)d_out;

    const size_t ND = (size_t)N_ROWS * DDIM;  // 4,194,304
    const size_t WD = (size_t)DDIM * DDIM;    // 262,144

    f16_t* ws = (f16_t*)d_ws;
    f16_t* xd_hi = ws;
    f16_t* xd_lo = ws + ND;
    f16_t* yd    = ws + 2 * ND;
    f16_t* xt_hi = ws + 3 * ND;
    f16_t* xt_lo = ws + 4 * ND;
    f16_t* W_hi  = ws + 5 * ND;
    f16_t* W_lo  = ws + 5 * ND + WD;

    // fused prep: dropout + fp16 splits (x, W) and fp16 cast (y)
    prep_all<<<4096 + 4096 + 256, 256, 0, stream>>>(
        x, mx, y, my, W, xd_hi, xd_lo, yd, W_hi, W_lo);

    // GEMM1: xt = xd @ W^T (8192x512), fp16 3-segment, 64x64 tiles
    gemm1_split<2, 2, 128, 8><<<128 * 8, 256, 0, stream>>>(
        xd_hi, xd_lo, W_hi, W_lo, xt_hi, xt_lo, DDIM);

    // GEMM2: out = sigmoid(xt @ yd^T), fp16 2-segment, 256x256 tiles
    gemm2_sig<<<1024, 512, 0, stream>>>(xt_hi, xt_lo, yd, out);
}

// Round 5
// 455.154 us; speedup vs baseline: 1.1629x; 1.0048x over previous
//
#include <hip/hip_runtime.h>
#include <stdint.h>

// BilinearDiscriminator: out = sigmoid((x*mask_x) @ W^T @ (y*mask_y)^T)
// fp16 asymmetric precision (R6, verified absmax 0.0078):
//   GEMM1: xt = xd @ W^T, fp16 hi/lo both sides, 3 segments -> xt ~22-bit.
//   GEMM2: xt (hi/lo) @ yd (single fp16 plane), 2 segments.
// R8: COUNTED-LGKM REGISTER PIPELINE in GEMM2. R7 taught: V+A register file
// is unified (128V+128A = 256/wave -> 2 waves/SIMD -> 1 block/CU no matter
// the LDS), so occupancy can't rise; the schedule must win at 8 waves.
// R4-R7 all paid lgkmcnt(0)+2 barriers around EVERY 16-MFMA cluster (~1000
// cyc overhead per 621-cyc cluster). Now: all planes double-buffered again
// (96 KiB), ONE vmcnt(0)+barrier per K-tile, and counted lgkmcnt(4) waits so
// each MFMA cluster's fragments were issued one cluster earlier (read latency
// off the critical path). Read groups G1={ah03,b} G2={ah47} G3={al03}
// G4={al47}; wait trace: LGKM(4)->G1, LGKM(4)->G2, LGKM(4)->G3, LGKM(0)->G4.
// Stage trace: Ah,Alo issued tile-top, B after M1; all drained by the single
// tile-end vmcnt(0) (issued ~2500 cyc earlier, L2-resident -> ~free).
// sched_barrier(0) after every counted wait (rule: compiler hoists reg-only
// MFMA past inline-asm waitcnt) and between G1/G2 issue (pins FIFO order).

typedef _Float16 f16_t;
typedef f16_t f16x8 __attribute__((ext_vector_type(8)));
typedef f16_t f16x4 __attribute__((ext_vector_type(4)));
typedef float f32x4 __attribute__((ext_vector_type(4)));

#define N_ROWS 8192
#define M_ROWS 8192
#define DDIM 512
#define BK 32

__device__ __forceinline__ void async_cp16(const f16_t* g, f16_t* l) {
    __builtin_amdgcn_global_load_lds(
        (const __attribute__((address_space(1))) unsigned int*)(uintptr_t)g,
        (__attribute__((address_space(3))) unsigned int*)(uint32_t)(uintptr_t)l,
        16, 0, 0);
}

#define VMCNT_(n) asm volatile("s_waitcnt vmcnt(" #n ")" ::: "memory")
#define VMCNT(n) VMCNT_(n)
#define LGKM_(n)  asm volatile("s_waitcnt lgkmcnt(" #n ")" ::: "memory")
#define LGKM(n)  LGKM_(n)
#define SB0()    __builtin_amdgcn_sched_barrier(0)
#define BAR()    __builtin_amdgcn_s_barrier()

// One kernel for all three dropout+split preps.
// blocks [0,4096): x -> hi/lo   [4096,8192): y -> single   [8192,8448): W -> hi/lo
__global__ __launch_bounds__(256) void prep_all(
    const float* __restrict__ x, const float* __restrict__ mx,
    const float* __restrict__ y, const float* __restrict__ my,
    const float* __restrict__ W,
    f16_t* __restrict__ xd_hi, f16_t* __restrict__ xd_lo,
    f16_t* __restrict__ yd,
    f16_t* __restrict__ W_hi, f16_t* __restrict__ W_lo) {
    const int b = blockIdx.x;
    const float* v; const float* m; f16_t* hi; f16_t* lo; int idx;
    if (b < 4096)      { v = x; m = mx;      hi = xd_hi; lo = xd_lo; idx = b * 256 + threadIdx.x; }
    else if (b < 8192) { v = y; m = my;      hi = yd;    lo = nullptr; idx = (b - 4096) * 256 + threadIdx.x; }
    else               { v = W; m = nullptr; hi = W_hi;  lo = W_lo;  idx = (b - 8192) * 256 + threadIdx.x; }
    float4 xv = ((const float4*)v)[idx];
    if (m) {
        float4 mv = ((const float4*)m)[idx];
        xv.x *= mv.x; xv.y *= mv.y; xv.z *= mv.z; xv.w *= mv.w;
    }
    float vals[4] = {xv.x, xv.y, xv.z, xv.w};
    f16x4 h, l;
#pragma unroll
    for (int i = 0; i < 4; ++i) {
        f16_t hh = (f16_t)vals[i];
        h[i] = hh;
        l[i] = (f16_t)(vals[i] - (float)hh);
    }
    *(f16x4*)(hi + (size_t)idx * 4) = h;
    if (lo) *(f16x4*)(lo + (size_t)idx * 4) = l;
}

// ---------------------------------------------------------------------------
// GEMM1 (64x64 tiles, old 2-barrier structure): xt = xd @ W^T, fp16 hi/lo on
// BOTH sides, 3 segments (hh + lh + hl) -> xt good to ~22 bits. Epilogue
// writes xt as fp16 hi/lo. Small kernel (1/16 of GEMM2's FLOPs).
// ---------------------------------------------------------------------------
template <int MI, int NI, int TM, int TN>
__global__ __launch_bounds__(256) void gemm1_split(
    const f16_t* __restrict__ Ahi, const f16_t* __restrict__ Alo,
    const f16_t* __restrict__ Bhi, const f16_t* __restrict__ Blo,
    f16_t* __restrict__ Chi, f16_t* __restrict__ Clo,
    int ldc) {
    constexpr int BM = MI * 32;
    constexpr int BN = NI * 32;
    constexpr int AS = BM * 4 / 256;
    constexpr int BS = BN * 4 / 256;
    constexpr int SN = TN / 8;

    __shared__ __align__(16) f16_t Ash[BM * BK];
    __shared__ __align__(16) f16_t Asl[BM * BK];
    __shared__ __align__(16) f16_t Bsh[BN * BK];
    __shared__ __align__(16) f16_t Bsl[BN * BK];

    const int tid = threadIdx.x;
    const int lane = tid & 63;
    const int wave = tid >> 6;
    const int wm = (wave & 1) * MI * 16;
    const int wn = (wave >> 1) * NI * 16;

    const int bid = blockIdx.x;
    const int jj = bid & 7;
    const int ii = (bid >> 3) & 7;
    const int sc = (bid >> 6) % SN;
    const int sr = (bid >> 6) / SN;
    const int bm = sr * 8 + ii;
    const int bn = sc * 8 + jj;

    const int m0 = lane & 15;
    const int kc = lane >> 4;
    const int fsw = kc ^ ((m0 >> 1) & 3);

    f32x4 acc[MI][NI];
#pragma unroll
    for (int i = 0; i < MI; ++i)
#pragma unroll
        for (int j = 0; j < NI; ++j)
            acc[i][j] = (f32x4){0.f, 0.f, 0.f, 0.f};

    for (int k0 = 0; k0 < DDIM; k0 += BK) {
        __syncthreads();
#pragma unroll
        for (int s = 0; s < AS; ++s) {
            const int slot = tid + s * 256;
            const int r = slot >> 2;
            const int c = (slot & 3) ^ ((r >> 1) & 3);
            const size_t g = (size_t)(bm * BM + r) * DDIM + k0 + c * 8;
            async_cp16(Ahi + g, &Ash[slot * 8]);
            async_cp16(Alo + g, &Asl[slot * 8]);
        }
#pragma unroll
        for (int s = 0; s < BS; ++s) {
            const int slot = tid + s * 256;
            const int r = slot >> 2;
            const int c = (slot & 3) ^ ((r >> 1) & 3);
            const size_t g = (size_t)(bn * BN + r) * DDIM + k0 + c * 8;
            async_cp16(Bhi + g, &Bsh[slot * 8]);
            async_cp16(Blo + g, &Bsl[slot * 8]);
        }
        __syncthreads();

        f16x8 ah[MI], bh[NI];
#pragma unroll
        for (int mi = 0; mi < MI; ++mi)
            ah[mi] = *(const f16x8*)&Ash[((wm + mi * 16 + m0) * 4 + fsw) * 8];
#pragma unroll
        for (int ni = 0; ni < NI; ++ni)
            bh[ni] = *(const f16x8*)&Bsh[((wn + ni * 16 + m0) * 4 + fsw) * 8];

#pragma unroll
        for (int mi = 0; mi < MI; ++mi)
#pragma unroll
            for (int ni = 0; ni < NI; ++ni)
                acc[mi][ni] = __builtin_amdgcn_mfma_f32_16x16x32_f16(
                    ah[mi], bh[ni], acc[mi][ni], 0, 0, 0);
        {
            f16x8 al[MI];
#pragma unroll
            for (int mi = 0; mi < MI; ++mi)
                al[mi] = *(const f16x8*)&Asl[((wm + mi * 16 + m0) * 4 + fsw) * 8];
#pragma unroll
            for (int mi = 0; mi < MI; ++mi)
#pragma unroll
                for (int ni = 0; ni < NI; ++ni)
                    acc[mi][ni] = __builtin_amdgcn_mfma_f32_16x16x32_f16(
                        al[mi], bh[ni], acc[mi][ni], 0, 0, 0);
        }
        {
            f16x8 bl[NI];
#pragma unroll
            for (int ni = 0; ni < NI; ++ni)
                bl[ni] = *(const f16x8*)&Bsl[((wn + ni * 16 + m0) * 4 + fsw) * 8];
#pragma unroll
            for (int mi = 0; mi < MI; ++mi)
#pragma unroll
                for (int ni = 0; ni < NI; ++ni)
                    acc[mi][ni] = __builtin_amdgcn_mfma_f32_16x16x32_f16(
                        ah[mi], bl[ni], acc[mi][ni], 0, 0, 0);
        }
    }

    const int ccol = lane & 15;
    const int crow = (lane >> 4) * 4;
#pragma unroll
    for (int mi = 0; mi < MI; ++mi) {
#pragma unroll
        for (int ni = 0; ni < NI; ++ni) {
#pragma unroll
            for (int r = 0; r < 4; ++r) {
                const int i = bm * BM + wm + mi * 16 + crow + r;
                const int j = bn * BN + wn + ni * 16 + ccol;
                const float v = acc[mi][ni][r];
                f16_t h = (f16_t)v;
                f16_t lo = (f16_t)(v - (float)h);
                Chi[(size_t)i * ldc + j] = h;
                Clo[(size_t)i * ldc + j] = lo;
            }
        }
    }
}

// ---------------------------------------------------------------------------
// GEMM2: out = sigmoid(xt @ yd^T), 8192x8192, K=512. 256x256 tile, 8 waves
// (2Mx4N), per-wave 128x64 output. A = xt (fp16 hi/lo), B = yd (single).
// All planes double-buffered (96 KiB, 1 block/CU -- reg-capped anyway).
// Per K-tile: ONE barrier, ONE vmcnt(0), counted lgkm pipeline:
//   issue {ah03,b} | SB0 | issue {ah47} + stage Ah,Alo(t+1)
//   LGKM(4) -> M1(ah03xb) | issue {al03} + stage B(t+1)
//   LGKM(4) -> M2(ah47xb) | issue {al47}
//   LGKM(4) -> M3(al03xb)
//   LGKM(0) -> M4(al47xb)
//   VMCNT(0) (6 loads issued ~2500 cyc ago, L2-resident -> ~free); BAR.
// Cross-wave safety: every wave drains its own stages (vmcnt 0) before BAR;
// after BAR all [nxt] buffers readable. Stage-over-read: [nxt] was last read
// in tile t-1, drained by each reader's lgkm before its own t-1 tile-end BAR.
// ---------------------------------------------------------------------------
__global__ __launch_bounds__(512, 2) void gemm2_sig(
    const f16_t* __restrict__ Ahi, const f16_t* __restrict__ Alo,
    const f16_t* __restrict__ Bh,
    float* __restrict__ Cf) {
    constexpr int BM = 256;           // = BN
    constexpr int LDT = BM * BK;      // 8192 f16 = 16 KiB per plane per buf

    __shared__ __align__(16) f16_t Ash[2][LDT];
    __shared__ __align__(16) f16_t Asl[2][LDT];
    __shared__ __align__(16) f16_t Bsh[2][LDT];

    const int tid = threadIdx.x;
    const int lane = tid & 63;
    const int wave = tid >> 6;
    const int wm = (wave >> 2) * 128;   // wave-row: 0 / 128
    const int wn = (wave & 3) * 64;     // wave-col: 0 / 64 / 128 / 192

    // supertile order (32x32 tile grid, 1024 blocks): bn fastest -> XCD id
    const int bid = blockIdx.x;
    const int jj = bid & 7;
    const int ii = (bid >> 3) & 7;
    const int sc = (bid >> 6) & 3;
    const int sr = (bid >> 6) >> 2;
    const int bm = sr * 8 + ii;
    const int bn = sc * 8 + jj;

    const int m0 = lane & 15;
    const int kc = lane >> 4;
    const int fsw = kc ^ ((m0 >> 1) & 3);  // swizzled chunk for fragment reads

    // per-thread staging map: 2 16B slots per plane per K-tile (1024 slots)
    int aOff[2], bOff[2], lofs[2];
#pragma unroll
    for (int s = 0; s < 2; ++s) {
        const int slot = tid + s * 512;
        const int r = slot >> 2;
        const int c = (slot & 3) ^ ((r >> 1) & 3);  // pre-swizzled global src
        aOff[s] = (bm * BM + r) * DDIM + c * 8;
        bOff[s] = (bn * BM + r) * DDIM + c * 8;
        lofs[s] = slot * 8;
    }

    f32x4 acc[8][4];
#pragma unroll
    for (int i = 0; i < 8; ++i)
#pragma unroll
        for (int j = 0; j < 4; ++j) acc[i][j] = (f32x4){0.f, 0.f, 0.f, 0.f};

    auto stageA = [&](const f16_t* g, f16_t* l, int k0) {
#pragma unroll
        for (int s = 0; s < 2; ++s) async_cp16(g + aOff[s] + k0, l + lofs[s]);
    };
    auto stageB = [&](const f16_t* g, f16_t* l, int k0) {
#pragma unroll
        for (int s = 0; s < 2; ++s) async_cp16(g + bOff[s] + k0, l + lofs[s]);
    };
    auto rdA = [&](const f16_t* s, int mi) {
        return *(const f16x8*)&s[((wm + mi * 16 + m0) * 4 + fsw) * 8];
    };
    auto rdB = [&](const f16_t* s, int ni) {
        return *(const f16x8*)&s[((wn + ni * 16 + m0) * 4 + fsw) * 8];
    };

    f16x8 ah[8], al[8], b[4];

#define MFMA16(AA, MI0)                                                   \
    _Pragma("unroll") for (int mi = 0; mi < 4; ++mi)                      \
    _Pragma("unroll") for (int ni = 0; ni < 4; ++ni)                      \
        acc[(MI0) + mi][ni] = __builtin_amdgcn_mfma_f32_16x16x32_f16(     \
            AA[(MI0) + mi], b[ni], acc[(MI0) + mi][ni], 0, 0, 0);

#define TILE(CUR, NXT, KNXT, STG)                                          \
    {                                                                      \
        const f16_t* ash = Ash[CUR]; const f16_t* asl = Asl[CUR];          \
        const f16_t* bsh = Bsh[CUR];                                       \
        /* G1: ah03 + b (8 ds_reads) */                                    \
        _Pragma("unroll") for (int i = 0; i < 4; ++i) ah[i] = rdA(ash, i); \
        _Pragma("unroll") for (int i = 0; i < 4; ++i) b[i]  = rdB(bsh, i); \
        SB0(); /* pin G1 before G2 in lgkm FIFO */                         \
        /* G2: ah47 (4 ds_reads) + stage Ah,Alo(t+1) */                    \
        _Pragma("unroll") for (int i = 4; i < 8; ++i) ah[i] = rdA(ash, i); \
        if (STG) { stageA(Ahi, Ash[NXT], (KNXT));                          \
                   stageA(Alo, Asl[NXT], (KNXT)); }                        \
        LGKM(4); SB0();  /* G1 landed (G2 still out) */                    \
        __builtin_amdgcn_s_setprio(1);                                     \
        MFMA16(ah, 0);                                                     \
        __builtin_amdgcn_s_setprio(0);                                     \
        /* G3: al03 + stage B(t+1) */                                      \
        _Pragma("unroll") for (int i = 0; i < 4; ++i) al[i] = rdA(asl, i); \
        if (STG) stageB(Bh, Bsh[NXT], (KNXT));                             \
        LGKM(4); SB0();  /* G2 landed (G3 still out) */                    \
        __builtin_amdgcn_s_setprio(1);                                     \
        MFMA16(ah, 4);                                                     \
        __builtin_amdgcn_s_setprio(0);                                     \
        /* G4: al47 */                                                     \
        _Pragma("unroll") for (int i = 4; i < 8; ++i) al[i] = rdA(asl, i); \
        LGKM(4); SB0();  /* G3 landed (G4 still out) */                    \
        __builtin_amdgcn_s_setprio(1);                                     \
        MFMA16(al, 0);                                                     \
        __builtin_amdgcn_s_setprio(0);                                     \
        LGKM(0); SB0();  /* G4 landed */                                   \
        __builtin_amdgcn_s_setprio(1);                                     \
        MFMA16(al, 4);                                                     \
        __builtin_amdgcn_s_setprio(0);                                     \
        if (STG) { VMCNT(0); BAR(); }                                      \
    }

    // prologue: stage tile 0 (Ah, Alo, B = 6 loads), drain, sync
    stageA(Ahi, Ash[0], 0);
    stageA(Alo, Asl[0], 0);
    stageB(Bh, Bsh[0], 0);
    VMCNT(0);
    BAR();

#pragma unroll 1
    for (int t2 = 0; t2 < 7; ++t2) {   // tiles 0..13
        const int kb = t2 * 2 * BK;
        TILE(0, 1, kb + BK, 1);
        TILE(1, 0, kb + 2 * BK, 1);
    }
    TILE(0, 1, 15 * BK, 1);            // tile 14, stages tile 15
    TILE(1, 0, 0, 0);                  // tile 15: no stage, no barrier

#undef TILE
#undef MFMA16

    // epilogue: sigmoid -> fp32, nontemporal (never re-read)
    const int ccol = lane & 15;
    const int crow = (lane >> 4) * 4;
#pragma unroll
    for (int mi = 0; mi < 8; ++mi) {
#pragma unroll
        for (int ni = 0; ni < 4; ++ni) {
#pragma unroll
            for (int r = 0; r < 4; ++r) {
                const size_t i = (size_t)(bm * BM + wm + mi * 16 + crow + r);
                const size_t j = (size_t)(bn * BM + wn + ni * 16 + ccol);
                const float v = acc[mi][ni][r];
                const float sv = 1.0f / (1.0f + __expf(-v));
                __builtin_nontemporal_store(sv, &Cf[i * M_ROWS + j]);
            }
        }
    }
}

extern "C" void kernel_launch(void* const* d_in, const int* in_sizes, int n_in,
                              void* d_out, int out_size, void* d_ws, size_t ws_size,
                              hipStream_t stream) {
    const float* x  = (const float*)d_in[0];
    const float* y  = (const float*)d_in[1];
    const float* mx = (const float*)d_in[2];
    const float* my = (const float*)d_in[3];
    const float* W  = (const float*)d_in[4];
    float* out = (float*)d_out;

    const size_t ND = (size_t)N_ROWS * DDIM;  // 4,194,304
    const size_t WD = (size_t)DDIM * DDIM;    // 262,144

    f16_t* ws = (f16_t*)d_ws;
    f16_t* xd_hi = ws;
    f16_t* xd_lo = ws + ND;
    f16_t* yd    = ws + 2 * ND;
    f16_t* xt_hi = ws + 3 * ND;
    f16_t* xt_lo = ws + 4 * ND;
    f16_t* W_hi  = ws + 5 * ND;
    f16_t* W_lo  = ws + 5 * ND + WD;

    // fused prep: dropout + fp16 splits (x, W) and fp16 cast (y)
    prep_all<<<4096 + 4096 + 256, 256, 0, stream>>>(
        x, mx, y, my, W, xd_hi, xd_lo, yd, W_hi, W_lo);

    // GEMM1: xt = xd @ W^T (8192x512), fp16 3-segment, 64x64 tiles
    gemm1_split<2, 2, 128, 8><<<128 * 8, 256, 0, stream>>>(
        xd_hi, xd_lo, W_hi, W_lo, xt_hi, xt_lo, DDIM);

    // GEMM2: out = sigmoid(xt @ yd^T), fp16 2-segment, 256x256 tiles
    gemm2_sig<<<1024, 512, 0, stream>>>(xt_hi, xt_lo, yd, out);
}